// Round 1
// baseline (1319.440 us; speedup 1.0000x reference)
//
#include <hip/hip_runtime.h>
#include <math.h>

#define NN 50000
#define EE 800000
#define RNA_D 645
#define SS_D 6
#define KFUSE 651
#define HD 128
#define GG 200

__device__ __forceinline__ float lrelu(float x){ return x >= 0.f ? x : 0.2f*x; }

// ---------------- graph prep ----------------
__global__ void hist_dst_kernel(const int* __restrict__ dst, int* __restrict__ deg){
  int e = blockIdx.x*256 + threadIdx.x;
  if (e < EE) atomicAdd(&deg[dst[e]], 1);
}
__global__ void hist_batch_kernel(const int* __restrict__ batch, int* __restrict__ cnt){
  int n = blockIdx.x*256 + threadIdx.x;
  if (n < NN) atomicAdd(&cnt[batch[n]], 1);
}
__global__ void scan1_kernel(const int* __restrict__ deg, int* __restrict__ row_start,
                             int* __restrict__ blocksum){
  __shared__ int s[256];
  int i = blockIdx.x*256 + threadIdx.x;
  int v = (i < NN) ? deg[i] : 0;
  s[threadIdx.x] = v;
  __syncthreads();
  for (int off=1; off<256; off<<=1){
    int t = (threadIdx.x >= off) ? s[threadIdx.x-off] : 0;
    __syncthreads();
    s[threadIdx.x] += t;
    __syncthreads();
  }
  if (i < NN) row_start[i] = s[threadIdx.x] - v;  // block-local exclusive
  if (threadIdx.x == 255) blocksum[blockIdx.x] = s[255];
}
__global__ void scan2_kernel(int* __restrict__ blocksum, int nb){
  __shared__ int s[256];
  int v = (threadIdx.x < nb) ? blocksum[threadIdx.x] : 0;
  s[threadIdx.x] = v;
  __syncthreads();
  for (int off=1; off<256; off<<=1){
    int t = (threadIdx.x >= off) ? s[threadIdx.x-off] : 0;
    __syncthreads();
    s[threadIdx.x] += t;
    __syncthreads();
  }
  blocksum[threadIdx.x] = s[threadIdx.x] - v;     // exclusive over block sums
}
__global__ void scan3_kernel(int* __restrict__ row_start, const int* __restrict__ blocksum,
                             int* __restrict__ cursor){
  int i = blockIdx.x*256 + threadIdx.x;
  if (i < NN){
    int v = row_start[i] + blocksum[blockIdx.x];
    row_start[i] = v;
    cursor[i] = v;
  }
  if (i == 0) row_start[NN] = EE;
}
__global__ void scatter_kernel(const int* __restrict__ srcl, const int* __restrict__ dstl,
                               int* __restrict__ cursor, int* __restrict__ csr_src){
  int e = blockIdx.x*256 + threadIdx.x;
  if (e >= EE) return;
  int d = dstl[e];
  int slot = atomicAdd(&cursor[d], 1);
  csr_src[slot] = srcl[e];
}

// ---------------- GEMM (32 rows x 128 cols per block, KT=64) ----------------
// MODE 0: fuse (A=rna|ss, K=651, epi: +bias, LN, relu)
// MODE 1: plain store (A stride 128)
// MODE 2: gate (A=h1|h2, K=256, epi: sigmoid(+bias) -> combine h1/h2)
// MODE 3: head (A stride 128, epi: +bias, LN, relu)
template<int MODE>
__launch_bounds__(256)
__global__ void gemm_kernel(const float* __restrict__ A0, const float* __restrict__ A1,
                            const float* __restrict__ W, const float* __restrict__ bias,
                            const float* __restrict__ gw, const float* __restrict__ gb,
                            float* __restrict__ out, int K){
  __shared__ float sA[32*68];
  __shared__ float sW[64*HD];
  int tid = threadIdx.x;
  int rg = tid >> 5, cg = tid & 31;          // 8 row-groups x 32 col-groups
  int rowBase = blockIdx.x * 32;
  float acc[4][4];
  #pragma unroll
  for (int j=0;j<4;++j){
    #pragma unroll
    for (int c=0;c<4;++c) acc[j][c]=0.f;
  }

  for (int k0 = 0; k0 < K; k0 += 64){
    #pragma unroll
    for (int i=0;i<8;++i){
      int idx = tid + i*256;
      int r = idx >> 6, kk = idx & 63;
      int gr = rowBase + r, gk = k0 + kk;
      float v = 0.f;
      if (gr < NN && gk < K){
        if (MODE == 0)      v = (gk < RNA_D) ? A0[(size_t)gr*RNA_D + gk] : A1[gr*SS_D + (gk - RNA_D)];
        else if (MODE == 2) v = (gk < HD) ? A0[gr*HD + gk] : A1[gr*HD + (gk - HD)];
        else                v = A0[gr*HD + gk];
      }
      sA[r*68 + kk] = v;
    }
    #pragma unroll
    for (int i=0;i<8;++i){
      int idx = tid + i*256;
      int k = idx >> 5, c4 = idx & 31;
      int gk = k0 + k;
      float4 v = make_float4(0.f,0.f,0.f,0.f);
      if (gk < K) v = *(const float4*)&W[gk*HD + c4*4];
      *(float4*)&sW[k*HD + c4*4] = v;
    }
    __syncthreads();
    #pragma unroll
    for (int kk=0; kk<64; kk+=4){
      float4 a4[4], w4[4];
      #pragma unroll
      for (int j=0;j<4;++j) a4[j] = *(float4*)&sA[(rg*4+j)*68 + kk];
      #pragma unroll
      for (int d=0;d<4;++d) w4[d] = *(float4*)&sW[(kk+d)*HD + cg*4];
      #pragma unroll
      for (int d=0;d<4;++d){
        #pragma unroll
        for (int j=0;j<4;++j){
          float a = ((const float*)&a4[j])[d];
          acc[j][0] = fmaf(a, w4[d].x, acc[j][0]);
          acc[j][1] = fmaf(a, w4[d].y, acc[j][1]);
          acc[j][2] = fmaf(a, w4[d].z, acc[j][2]);
          acc[j][3] = fmaf(a, w4[d].w, acc[j][3]);
        }
      }
    }
    __syncthreads();
  }

  if (MODE == 1){
    #pragma unroll
    for (int j=0;j<4;++j){
      int gr = rowBase + rg*4 + j;
      if (gr < NN){
        float4 v = make_float4(acc[j][0],acc[j][1],acc[j][2],acc[j][3]);
        *(float4*)&out[gr*HD + cg*4] = v;
      }
    }
  } else if (MODE == 2){
    float4 b4 = *(const float4*)&bias[cg*4];
    #pragma unroll
    for (int j=0;j<4;++j){
      int gr = rowBase + rg*4 + j;
      if (gr < NN){
        float4 x1 = *(const float4*)&A0[gr*HD + cg*4];
        float4 x2 = *(const float4*)&A1[gr*HD + cg*4];
        float g0 = 1.f/(1.f + __expf(-(acc[j][0] + b4.x)));
        float g1 = 1.f/(1.f + __expf(-(acc[j][1] + b4.y)));
        float g2 = 1.f/(1.f + __expf(-(acc[j][2] + b4.z)));
        float g3 = 1.f/(1.f + __expf(-(acc[j][3] + b4.w)));
        float4 v;
        v.x = g0*x1.x + (1.f-g0)*x2.x;
        v.y = g1*x1.y + (1.f-g1)*x2.y;
        v.z = g2*x1.z + (1.f-g2)*x2.z;
        v.w = g3*x1.w + (1.f-g3)*x2.w;
        *(float4*)&out[gr*HD + cg*4] = v;
      }
    }
  } else { // MODE 0 or 3: +bias, LayerNorm over 128 cols, relu
    float4 b4 = *(const float4*)&bias[cg*4];
    #pragma unroll
    for (int j=0;j<4;++j){
      acc[j][0]+=b4.x; acc[j][1]+=b4.y; acc[j][2]+=b4.z; acc[j][3]+=b4.w;
    }
    float* redS = sW;              // 32*33 floats
    float* redQ = sW + 32*33;      // 32*33 floats
    #pragma unroll
    for (int j=0;j<4;++j){
      float s = acc[j][0]+acc[j][1]+acc[j][2]+acc[j][3];
      float q = acc[j][0]*acc[j][0]+acc[j][1]*acc[j][1]+acc[j][2]*acc[j][2]+acc[j][3]*acc[j][3];
      redS[(rg*4+j)*33 + cg] = s;
      redQ[(rg*4+j)*33 + cg] = q;
    }
    __syncthreads();
    float* mv = sA;
    if (tid < 32){
      float s=0.f, q=0.f;
      #pragma unroll
      for (int i=0;i<32;++i){ s += redS[tid*33+i]; q += redQ[tid*33+i]; }
      float mean = s * (1.f/128.f);
      float var  = q * (1.f/128.f) - mean*mean;
      mv[tid*2]   = mean;
      mv[tid*2+1] = rsqrtf(var + 1e-5f);
    }
    __syncthreads();
    float4 g4  = *(const float4*)&gw[cg*4];
    float4 bb4 = *(const float4*)&gb[cg*4];
    #pragma unroll
    for (int j=0;j<4;++j){
      int gr = rowBase + rg*4 + j;
      if (gr < NN){
        float mean = mv[(rg*4+j)*2], inv = mv[(rg*4+j)*2+1];
        float4 v;
        v.x = fmaxf((acc[j][0]-mean)*inv*g4.x + bb4.x, 0.f);
        v.y = fmaxf((acc[j][1]-mean)*inv*g4.y + bb4.y, 0.f);
        v.z = fmaxf((acc[j][2]-mean)*inv*g4.z + bb4.z, 0.f);
        v.w = fmaxf((acc[j][3]-mean)*inv*g4.w + bb4.w, 0.f);
        *(float4*)&out[gr*HD + cg*4] = v;
      }
    }
  }
}

// ---------------- fc1: [N,128]@[128,64] + LN(64) + relu ----------------
__launch_bounds__(256)
__global__ void fc1_kernel(const float* __restrict__ A, const float* __restrict__ W,
                           const float* __restrict__ bias, const float* __restrict__ gw,
                           const float* __restrict__ gb, float* __restrict__ out){
  __shared__ float sA[64*68];
  __shared__ float sW[64*64];
  int tid = threadIdx.x;
  int rg = tid >> 4, cg = tid & 15;          // 16 row-groups x 16 col-groups
  int rowBase = blockIdx.x * 64;
  float acc[4][4];
  #pragma unroll
  for (int j=0;j<4;++j){
    #pragma unroll
    for (int c=0;c<4;++c) acc[j][c]=0.f;
  }
  for (int k0=0;k0<HD;k0+=64){
    #pragma unroll
    for (int i=0;i<16;++i){
      int idx = tid + i*256;
      int r = idx >> 6, kk = idx & 63;
      int gr = rowBase + r;
      float v = 0.f;
      if (gr < NN) v = A[gr*HD + k0 + kk];
      sA[r*68 + kk] = v;
    }
    #pragma unroll
    for (int i=0;i<4;++i){
      int idx = tid + i*256;
      int k = idx >> 4, c4 = idx & 15;
      *(float4*)&sW[k*64 + c4*4] = *(const float4*)&W[(k0+k)*64 + c4*4];
    }
    __syncthreads();
    #pragma unroll
    for (int kk=0;kk<64;kk+=4){
      float4 a4[4], w4[4];
      #pragma unroll
      for (int j=0;j<4;++j) a4[j] = *(float4*)&sA[(rg*4+j)*68 + kk];
      #pragma unroll
      for (int d=0;d<4;++d) w4[d] = *(float4*)&sW[(kk+d)*64 + cg*4];
      #pragma unroll
      for (int d=0;d<4;++d){
        #pragma unroll
        for (int j=0;j<4;++j){
          float a = ((const float*)&a4[j])[d];
          acc[j][0] = fmaf(a, w4[d].x, acc[j][0]);
          acc[j][1] = fmaf(a, w4[d].y, acc[j][1]);
          acc[j][2] = fmaf(a, w4[d].z, acc[j][2]);
          acc[j][3] = fmaf(a, w4[d].w, acc[j][3]);
        }
      }
    }
    __syncthreads();
  }
  float4 b4 = *(const float4*)&bias[cg*4];
  #pragma unroll
  for (int j=0;j<4;++j){
    acc[j][0]+=b4.x; acc[j][1]+=b4.y; acc[j][2]+=b4.z; acc[j][3]+=b4.w;
  }
  float* redS = sW;             // 64*17
  float* redQ = sW + 64*17;     // 64*17
  #pragma unroll
  for (int j=0;j<4;++j){
    float s = acc[j][0]+acc[j][1]+acc[j][2]+acc[j][3];
    float q = acc[j][0]*acc[j][0]+acc[j][1]*acc[j][1]+acc[j][2]*acc[j][2]+acc[j][3]*acc[j][3];
    redS[(rg*4+j)*17 + cg] = s;
    redQ[(rg*4+j)*17 + cg] = q;
  }
  __syncthreads();
  float* mv = sA;
  if (tid < 64){
    float s=0.f,q=0.f;
    #pragma unroll
    for (int i=0;i<16;++i){ s += redS[tid*17+i]; q += redQ[tid*17+i]; }
    float mean = s * (1.f/64.f);
    float var  = q * (1.f/64.f) - mean*mean;
    mv[tid*2]   = mean;
    mv[tid*2+1] = rsqrtf(var + 1e-5f);
  }
  __syncthreads();
  float4 g4  = *(const float4*)&gw[cg*4];
  float4 bb4 = *(const float4*)&gb[cg*4];
  #pragma unroll
  for (int j=0;j<4;++j){
    int gr = rowBase + rg*4 + j;
    if (gr < NN){
      float mean = mv[(rg*4+j)*2], inv = mv[(rg*4+j)*2+1];
      float4 v;
      v.x = fmaxf((acc[j][0]-mean)*inv*g4.x + bb4.x, 0.f);
      v.y = fmaxf((acc[j][1]-mean)*inv*g4.y + bb4.y, 0.f);
      v.z = fmaxf((acc[j][2]-mean)*inv*g4.z + bb4.z, 0.f);
      v.w = fmaxf((acc[j][3]-mean)*inv*g4.w + bb4.w, 0.f);
      *(float4*)&out[gr*64 + cg*4] = v;
    }
  }
}

// ---------------- GAT pieces ----------------
__launch_bounds__(256)
__global__ void esed_kernel(const float* __restrict__ xw, const float* __restrict__ as,
                            const float* __restrict__ ad, float* __restrict__ es,
                            float* __restrict__ ed){
  int gid = blockIdx.x*256 + threadIdx.x;
  int n = gid >> 6, lane = gid & 63;
  if (n >= NN) return;
  float x0 = xw[n*HD + lane], x1 = xw[n*HD + 64 + lane];
  float s = x0*as[lane] + x1*as[64+lane];
  float d = x0*ad[lane] + x1*ad[64+lane];
  #pragma unroll
  for (int off=32; off; off>>=1){ s += __shfl_down(s, off); d += __shfl_down(d, off); }
  if (lane == 0){ es[n] = s; ed[n] = d; }
}

__launch_bounds__(256)
__global__ void gat_aggregate_kernel(const float* __restrict__ xw, const float* __restrict__ es,
                                     const float* __restrict__ ed, const int* __restrict__ row_start,
                                     const int* __restrict__ csr_src, const float* __restrict__ bgat,
                                     float* __restrict__ out){
  int gid = blockIdx.x*256 + threadIdx.x;
  int n = gid >> 6, lane = gid & 63;
  if (n >= NN) return;
  int beg = row_start[n], end = row_start[n+1];
  float edn = ed[n];
  float sc_self = lrelu(es[n] + edn);
  float m = sc_self;
  for (int i = beg + lane; i < end; i += 64)
    m = fmaxf(m, lrelu(es[csr_src[i]] + edn));
  #pragma unroll
  for (int off=32; off; off>>=1) m = fmaxf(m, __shfl_xor(m, off));
  float ssum = 0.f;
  for (int i = beg + lane; i < end; i += 64)
    ssum += __expf(lrelu(es[csr_src[i]] + edn) - m);
  #pragma unroll
  for (int off=32; off; off>>=1) ssum += __shfl_xor(ssum, off);
  ssum += __expf(sc_self - m);
  float dinv = 1.f/(ssum + 1e-16f);
  float wse = __expf(sc_self - m) * dinv;
  float a0 = wse * xw[n*HD + lane];
  float a1 = wse * xw[n*HD + 64 + lane];
  for (int i = beg; i < end; ++i){
    int s = csr_src[i];
    float w = __expf(lrelu(es[s] + edn) - m) * dinv;
    a0 = fmaf(w, xw[s*HD + lane], a0);
    a1 = fmaf(w, xw[s*HD + 64 + lane], a1);
  }
  out[n*HD + lane]      = a0 + bgat[lane];
  out[n*HD + 64 + lane] = a1 + bgat[64 + lane];
}

// ---------------- GraphNorm ----------------
__launch_bounds__(128)
__global__ void gn_stats_kernel(const float* __restrict__ x, const int* __restrict__ batch,
                                float* __restrict__ gsum, float* __restrict__ gsq){
  int f = threadIdx.x;
  int n0 = blockIdx.x * 64;
  if (n0 >= NN) return;
  int n1 = min(n0 + 64, NN);
  int cur = batch[n0];
  float s = 0.f, q = 0.f;
  for (int n = n0; n < n1; ++n){
    int g = batch[n];
    if (g != cur){
      atomicAdd(&gsum[cur*HD + f], s);
      atomicAdd(&gsq[cur*HD + f], q);
      s = 0.f; q = 0.f; cur = g;
    }
    float v = x[(size_t)n*HD + f];
    s += v; q = fmaf(v, v, q);
  }
  atomicAdd(&gsum[cur*HD + f], s);
  atomicAdd(&gsq[cur*HD + f], q);
}

__global__ void gn_final_kernel(const float* __restrict__ gsum, const float* __restrict__ gsq,
                                const int* __restrict__ cnt, const float* __restrict__ gnw,
                                const float* __restrict__ gnms, float* __restrict__ shiftv,
                                float* __restrict__ scalev){
  int idx = blockIdx.x*256 + threadIdx.x;
  if (idx >= GG*HD) return;
  int f = idx & (HD-1);
  int g = idx >> 7;
  float c = fmaxf((float)cnt[g], 1.f);
  float mean = gsum[idx] / c;
  float ms = gnms[f];
  // var of (x - ms*mean): E[x^2] - mean^2 * ms * (2 - ms)
  float var = gsq[idx]/c - mean*mean*ms*(2.f - ms);
  shiftv[idx] = ms*mean;
  scalev[idx] = gnw[f] / sqrtf(var + 1e-5f);
}

template<bool RES>
__launch_bounds__(256)
__global__ void gn_norm_kernel(const float* __restrict__ x, const int* __restrict__ batch,
                               const float* __restrict__ shiftv, const float* __restrict__ scalev,
                               const float* __restrict__ gnb, const float* __restrict__ res,
                               float* __restrict__ out){
  int idx = blockIdx.x*256 + threadIdx.x;   // float4 index
  if (idx >= NN*32) return;
  int n = idx >> 5, c4 = idx & 31;
  int f = c4*4;
  int g = batch[n];
  float4 xv = *(const float4*)&x[n*HD + f];
  float4 sh = *(const float4*)&shiftv[g*HD + f];
  float4 sc = *(const float4*)&scalev[g*HD + f];
  float4 bb = *(const float4*)&gnb[f];
  float4 v;
  v.x = fmaxf((xv.x - sh.x)*sc.x + bb.x, 0.f);
  v.y = fmaxf((xv.y - sh.y)*sc.y + bb.y, 0.f);
  v.z = fmaxf((xv.z - sh.z)*sc.z + bb.z, 0.f);
  v.w = fmaxf((xv.w - sh.w)*sc.w + bb.w, 0.f);
  if (RES){
    float4 r = *(const float4*)&res[n*HD + f];
    v.x += r.x; v.y += r.y; v.z += r.z; v.w += r.w;
  }
  *(float4*)&out[n*HD + f] = v;
}

// ---------------- fc2: [N,64]@[64,1] ----------------
__launch_bounds__(256)
__global__ void fc2_kernel(const float* __restrict__ x, const float* __restrict__ w,
                           const float* __restrict__ b, float* __restrict__ out){
  int gid = blockIdx.x*256 + threadIdx.x;
  int n = gid >> 6, lane = gid & 63;
  if (n >= NN) return;
  float v = x[n*64 + lane] * w[lane];
  #pragma unroll
  for (int off=32; off; off>>=1) v += __shfl_down(v, off);
  if (lane == 0) out[n] = v + b[0];
}

// ---------------- launch ----------------
extern "C" void kernel_launch(void* const* d_in, const int* in_sizes, int n_in,
                              void* d_out, int out_size, void* d_ws, size_t ws_size,
                              hipStream_t stream){
  const float* rna    = (const float*)d_in[0];
  const float* ss     = (const float*)d_in[1];
  const int*   eidx   = (const int*)d_in[2];
  const int*   batch  = (const int*)d_in[3];
  const float* W_fuse = (const float*)d_in[4];
  const float* b_fuse = (const float*)d_in[5];
  const float* ln1_g  = (const float*)d_in[6];
  const float* ln1_b  = (const float*)d_in[7];
  const float* W_gat  = (const float*)d_in[8];
  const float* att_src= (const float*)d_in[9];
  const float* att_dst= (const float*)d_in[10];
  const float* b_gat  = (const float*)d_in[11];
  const float* gn_w   = (const float*)d_in[12];
  const float* gn_b   = (const float*)d_in[13];
  const float* gn_ms  = (const float*)d_in[14];
  const float* W_gate = (const float*)d_in[15];
  const float* b_gate = (const float*)d_in[16];
  const float* W_head = (const float*)d_in[17];
  const float* b_head = (const float*)d_in[18];
  const float* ln2_g  = (const float*)d_in[19];
  const float* ln2_b  = (const float*)d_in[20];
  const float* W_fc1  = (const float*)d_in[21];
  const float* b_fc1  = (const float*)d_in[22];
  const float* ln3_g  = (const float*)d_in[23];
  const float* ln3_b  = (const float*)d_in[24];
  const float* W_fc2  = (const float*)d_in[25];
  const float* b_fc2  = (const float*)d_in[26];
  float* outp = (float*)d_out;

  const int* srcl = eidx;
  const int* dstl = eidx + EE;

  float* F = (float*)d_ws;
  size_t off = 0;
  auto alloc = [&](size_t nelem)->float*{
    float* p = F + off; off += (nelem + 63) & ~(size_t)63; return p;
  };
  float* h    = alloc((size_t)NN*HD);
  float* h1   = alloc((size_t)NN*HD);
  float* h2   = alloc((size_t)NN*HD);
  float* xw   = alloc((size_t)NN*HD);
  float* y    = alloc((size_t)NN*HD);
  float* es   = alloc(NN);
  float* ed   = alloc(NN);
  float* gsum = alloc(GG*HD);   // contiguous with gsq (both multiples of 64)
  float* gsq  = alloc(GG*HD);
  float* shiftv = alloc(GG*HD);
  float* scalev = alloc(GG*HD);
  int* deg       = (int*)alloc(NN);
  int* row_start = (int*)alloc(NN + 64);
  int* cursor    = (int*)alloc(NN);
  int* csr_src   = (int*)alloc(EE);
  int* blocksum  = (int*)alloc(256);
  int* cnt       = (int*)alloc(GG);
  float* hg = xw;   // reuse
  float* t1 = y;    // reuse
  float* t2 = h;    // reuse

  const int NB = (NN + 255)/256;          // 196
  const int GB = (NN + 31)/32;            // 1563
  const int EB = (EE + 255)/256;          // 3125
  const int WVB = (NN*64 + 255)/256;      // 12500

  hipMemsetAsync(deg, 0, NN*sizeof(int), stream);
  hipMemsetAsync(cnt, 0, GG*sizeof(int), stream);
  hist_dst_kernel<<<EB, 256, 0, stream>>>(dstl, deg);
  hist_batch_kernel<<<NB, 256, 0, stream>>>(batch, cnt);
  scan1_kernel<<<NB, 256, 0, stream>>>(deg, row_start, blocksum);
  scan2_kernel<<<1, 256, 0, stream>>>(blocksum, NB);
  scan3_kernel<<<NB, 256, 0, stream>>>(row_start, blocksum, cursor);
  scatter_kernel<<<EB, 256, 0, stream>>>(srcl, dstl, cursor, csr_src);

  // fuse + LN1 + relu -> h
  gemm_kernel<0><<<GB, 256, 0, stream>>>(rna, ss, W_fuse, b_fuse, ln1_g, ln1_b, h, KFUSE);

  // ---- GAT layer 1 ----
  gemm_kernel<1><<<GB, 256, 0, stream>>>(h, nullptr, W_gat, nullptr, nullptr, nullptr, xw, HD);
  esed_kernel<<<WVB, 256, 0, stream>>>(xw, att_src, att_dst, es, ed);
  gat_aggregate_kernel<<<WVB, 256, 0, stream>>>(xw, es, ed, row_start, csr_src, b_gat, y);
  hipMemsetAsync(gsum, 0, (size_t)2*GG*HD*sizeof(float), stream);
  gn_stats_kernel<<<(NN+63)/64, 128, 0, stream>>>(y, batch, gsum, gsq);
  gn_final_kernel<<<(GG*HD+255)/256, 256, 0, stream>>>(gsum, gsq, cnt, gn_w, gn_ms, shiftv, scalev);
  gn_norm_kernel<false><<<(NN*32+255)/256, 256, 0, stream>>>(y, batch, shiftv, scalev, gn_b, nullptr, h1);

  // ---- GAT layer 2 ----
  gemm_kernel<1><<<GB, 256, 0, stream>>>(h1, nullptr, W_gat, nullptr, nullptr, nullptr, xw, HD);
  esed_kernel<<<WVB, 256, 0, stream>>>(xw, att_src, att_dst, es, ed);
  gat_aggregate_kernel<<<WVB, 256, 0, stream>>>(xw, es, ed, row_start, csr_src, b_gat, y);
  hipMemsetAsync(gsum, 0, (size_t)2*GG*HD*sizeof(float), stream);
  gn_stats_kernel<<<(NN+63)/64, 128, 0, stream>>>(y, batch, gsum, gsq);
  gn_final_kernel<<<(GG*HD+255)/256, 256, 0, stream>>>(gsum, gsq, cnt, gn_w, gn_ms, shiftv, scalev);
  gn_norm_kernel<true><<<(NN*32+255)/256, 256, 0, stream>>>(y, batch, shiftv, scalev, gn_b, h, h2);

  // gate combine -> hg (reuses xw)
  gemm_kernel<2><<<GB, 256, 0, stream>>>(h1, h2, W_gate, b_gate, nullptr, nullptr, hg, 2*HD);
  // head + LN2 + relu -> t1 (reuses y)
  gemm_kernel<3><<<GB, 256, 0, stream>>>(hg, nullptr, W_head, b_head, ln2_g, ln2_b, t1, HD);
  // fc1 + LN3 + relu -> t2 (reuses h)
  fc1_kernel<<<(NN+63)/64, 256, 0, stream>>>(t1, W_fc1, b_fc1, ln3_g, ln3_b, t2);
  // fc2 -> out
  fc2_kernel<<<WVB, 256, 0, stream>>>(t2, W_fc2, b_fc2, outp);
}

// Round 2
// 944.669 us; speedup vs baseline: 1.3967x; 1.3967x over previous
//
#include <hip/hip_runtime.h>
#include <hip/hip_bf16.h>
#include <math.h>

#define NN 50000
#define EE 800000
#define RNA_D 645
#define KFUSE 651
#define HD 128
#define GG 200
#define SAK 72   // LDS k-stride (bf16 elems): 64 + 8 pad, 144B rows (16B-aligned, bank-spread)

typedef __attribute__((ext_vector_type(8))) short shortx8;
typedef __attribute__((ext_vector_type(4))) float floatx4;

__device__ __forceinline__ float lrelu(float x){ return x >= 0.f ? x : 0.2f*x; }
__device__ __forceinline__ short f2bf(float x){
  union { __hip_bfloat16 h; short s; } u; u.h = __float2bfloat16(x); return u.s;
}

// ---------------- graph prep ----------------
__global__ void hist_dst_kernel(const int* __restrict__ dst, int* __restrict__ deg){
  int e = blockIdx.x*256 + threadIdx.x;
  if (e < EE) atomicAdd(&deg[dst[e]], 1);
}
__global__ void scan1_kernel(const int* __restrict__ deg, int* __restrict__ row_start,
                             int* __restrict__ blocksum){
  __shared__ int s[256];
  int i = blockIdx.x*256 + threadIdx.x;
  int v = (i < NN) ? deg[i] : 0;
  s[threadIdx.x] = v;
  __syncthreads();
  for (int off=1; off<256; off<<=1){
    int t = (threadIdx.x >= off) ? s[threadIdx.x-off] : 0;
    __syncthreads();
    s[threadIdx.x] += t;
    __syncthreads();
  }
  if (i < NN) row_start[i] = s[threadIdx.x] - v;
  if (threadIdx.x == 255) blocksum[blockIdx.x] = s[255];
}
__global__ void scan2_kernel(int* __restrict__ blocksum, int nb){
  __shared__ int s[256];
  int v = (threadIdx.x < nb) ? blocksum[threadIdx.x] : 0;
  s[threadIdx.x] = v;
  __syncthreads();
  for (int off=1; off<256; off<<=1){
    int t = (threadIdx.x >= off) ? s[threadIdx.x-off] : 0;
    __syncthreads();
    s[threadIdx.x] += t;
    __syncthreads();
  }
  blocksum[threadIdx.x] = s[threadIdx.x] - v;
}
__global__ void scan3_kernel(int* __restrict__ row_start, const int* __restrict__ blocksum,
                             int* __restrict__ cursor){
  int i = blockIdx.x*256 + threadIdx.x;
  if (i < NN){
    int v = row_start[i] + blocksum[blockIdx.x];
    row_start[i] = v;
    cursor[i] = v;
  }
  if (i == 0) row_start[NN] = EE;
}
__global__ void scatter_kernel(const int* __restrict__ srcl, const int* __restrict__ dstl,
                               int* __restrict__ cursor, int* __restrict__ csr_src){
  int e = blockIdx.x*256 + threadIdx.x;
  if (e >= EE) return;
  int d = dstl[e];
  int slot = atomicAdd(&cursor[d], 1);
  csr_src[slot] = srcl[e];
}
__global__ void gstart_kernel(const int* __restrict__ batch, int* __restrict__ gstart){
  int n = blockIdx.x*256 + threadIdx.x;
  if (n >= NN) return;
  int g = batch[n];
  if (n == 0){ for (int gg=0; gg<=g; ++gg) gstart[gg] = 0; }
  else { int gp = batch[n-1]; for (int gg=gp+1; gg<=g; ++gg) gstart[gg] = n; }
  if (n == NN-1){ for (int gg=g+1; gg<=GG; ++gg) gstart[gg] = NN; }
}

// ---------------- weight prep: W[K][N] fp32 -> Wt[N][Kp] bf16 (zero-padded) ----
__global__ void wprep_kernel(const float* __restrict__ W, short* __restrict__ Wt,
                             int K, int N, int Kp){
  int idx = blockIdx.x*256 + threadIdx.x;
  if (idx >= N*Kp) return;
  int n = idx / Kp, k = idx - n*Kp;
  float v = (k < K) ? W[k*N + n] : 0.f;
  Wt[idx] = f2bf(v);
}

// ---------------- MFMA GEMM ----------------
// 128 rows x (NT*16) cols per block, 256 threads = 4 waves.
// Wave w: rows [w*32, w*32+32) as 2 row-tiles x NT col-tiles of 16x16x32 bf16 MFMA.
// MODE 0: fuse   A=concat(rna,ss) K=651  epi: +bias, LN(128), relu
// MODE 1: xw     A stride 128     K=128  epi: store + es/ed (fused edge-score proj)
// MODE 2: gate   A=h1|h2          K=256  epi: sigmoid(+bias) combine h1/h2
// MODE 3: head   A stride 128     K=128  epi: +bias, LN(128), relu
// MODE 4: fc1    A stride 128     K=128  epi: +bias, LN(64), relu   (NT=4)
template<int MODE, int NT>
__launch_bounds__(256)
__global__ void mfma_gemm(const float* __restrict__ A0, const float* __restrict__ A1,
                          const short* __restrict__ Wt, const float* __restrict__ bias,
                          const float* __restrict__ gw, const float* __restrict__ gb,
                          const float* __restrict__ as_, const float* __restrict__ ad_,
                          float* __restrict__ out, float* __restrict__ es, float* __restrict__ ed,
                          int K, int Kp){
  __shared__ short sA[128*SAK];
  __shared__ short sB[NT*16*SAK];
  const int tid  = threadIdx.x;
  const int wave = tid >> 6, lane = tid & 63;
  const int quad = lane >> 4, l16 = lane & 15;
  const int rowBase = blockIdx.x * 128;
  const int NCOL = NT*16;

  floatx4 acc[2][NT];
  #pragma unroll
  for (int t=0;t<2;++t)
    #pragma unroll
    for (int ct=0;ct<NT;++ct)
      #pragma unroll
      for (int j=0;j<4;++j) acc[t][ct][j] = 0.f;

  const int srow = tid >> 1, shalf = tid & 1;
  const int sgr = rowBase + srow;

  for (int k0 = 0; k0 < K; k0 += 64){
    // ---- stage A (fp32 -> bf16) ----
    {
      int kb = k0 + shalf*32;
      short tmp[32];
      if (MODE == 0){
        #pragma unroll
        for (int j=0;j<32;++j){
          int gk = kb + j;
          float v = 0.f;
          if (sgr < NN){
            if (gk < RNA_D)      v = A0[(size_t)sgr*RNA_D + gk];
            else if (gk < KFUSE) v = A1[sgr*6 + (gk - RNA_D)];
          }
          tmp[j] = f2bf(v);
        }
      } else {
        const float* p;
        if (MODE == 2) p = (kb < HD) ? (A0 + (size_t)sgr*HD + kb) : (A1 + (size_t)sgr*HD + (kb - HD));
        else           p = A0 + (size_t)sgr*HD + kb;
        #pragma unroll
        for (int q4=0;q4<8;++q4){
          float4 f = (sgr < NN) ? *(const float4*)(p + q4*4) : make_float4(0.f,0.f,0.f,0.f);
          tmp[q4*4+0] = f2bf(f.x); tmp[q4*4+1] = f2bf(f.y);
          tmp[q4*4+2] = f2bf(f.z); tmp[q4*4+3] = f2bf(f.w);
        }
      }
      #pragma unroll
      for (int q8=0;q8<4;++q8)
        *(shortx8*)&sA[srow*SAK + shalf*32 + q8*8] = *(shortx8*)&tmp[q8*8];
    }
    // ---- stage B (already bf16, [n][k] layout) ----
    if (NT == 8){
      int col = tid >> 1, kb = k0 + (tid&1)*32;
      #pragma unroll
      for (int q8=0;q8<4;++q8)
        *(shortx8*)&sB[col*SAK + (tid&1)*32 + q8*8] = *(const shortx8*)&Wt[(size_t)col*Kp + kb + q8*8];
    } else {
      if (tid < NT*32){
        int col = tid >> 1, kb = k0 + (tid&1)*32;
        #pragma unroll
        for (int q8=0;q8<4;++q8)
          *(shortx8*)&sB[col*SAK + (tid&1)*32 + q8*8] = *(const shortx8*)&Wt[(size_t)col*Kp + kb + q8*8];
      }
    }
    __syncthreads();
    // ---- MFMA ----
    #pragma unroll
    for (int ks=0; ks<2; ++ks){
      int kb = ks*32 + quad*8;
      shortx8 af0 = *(const shortx8*)&sA[(wave*32 +      l16)*SAK + kb];
      shortx8 af1 = *(const shortx8*)&sA[(wave*32 + 16 + l16)*SAK + kb];
      #pragma unroll
      for (int ct=0; ct<NT; ++ct){
        shortx8 bf = *(const shortx8*)&sB[(ct*16 + l16)*SAK + kb];
        acc[0][ct] = __builtin_amdgcn_mfma_f32_16x16x32_bf16(af0, bf, acc[0][ct], 0,0,0);
        acc[1][ct] = __builtin_amdgcn_mfma_f32_16x16x32_bf16(af1, bf, acc[1][ct], 0,0,0);
      }
    }
    __syncthreads();
  }

  // ---- epilogue ----
  if (MODE == 1){
    float asv[NT], adv[NT];
    #pragma unroll
    for (int ct=0;ct<NT;++ct){ asv[ct] = as_[ct*16+l16]; adv[ct] = ad_[ct*16+l16]; }
    #pragma unroll
    for (int t=0;t<2;++t)
      #pragma unroll
      for (int i=0;i<4;++i){
        int gr = rowBase + wave*32 + t*16 + quad*4 + i;
        float s=0.f, d=0.f;
        #pragma unroll
        for (int ct=0;ct<NT;++ct){
          float v = acc[t][ct][i];
          s = fmaf(v, asv[ct], s); d = fmaf(v, adv[ct], d);
          if (gr < NN) out[(size_t)gr*HD + ct*16 + l16] = v;
        }
        #pragma unroll
        for (int off=1; off<16; off<<=1){ s += __shfl_xor(s,off); d += __shfl_xor(d,off); }
        if (l16 == 0 && gr < NN){ es[gr] = s; ed[gr] = d; }
      }
  } else if (MODE == 2){
    float biasv[NT];
    #pragma unroll
    for (int ct=0;ct<NT;++ct) biasv[ct] = bias[ct*16+l16];
    #pragma unroll
    for (int t=0;t<2;++t)
      #pragma unroll
      for (int i=0;i<4;++i){
        int gr = rowBase + wave*32 + t*16 + quad*4 + i;
        if (gr < NN){
          #pragma unroll
          for (int ct=0;ct<NT;++ct){
            int c = ct*16 + l16;
            float g = 1.f/(1.f + __expf(-(acc[t][ct][i] + biasv[ct])));
            float x1 = A0[(size_t)gr*HD + c];
            float x2 = A1[(size_t)gr*HD + c];
            out[(size_t)gr*HD + c] = g*x1 + (1.f-g)*x2;
          }
        }
      }
  } else { // MODE 0 / 3 / 4 : +bias, LN(NCOL), relu
    float biasv[NT], gv[NT], bv[NT];
    #pragma unroll
    for (int ct=0;ct<NT;++ct){
      biasv[ct] = bias[ct*16+l16]; gv[ct] = gw[ct*16+l16]; bv[ct] = gb[ct*16+l16];
    }
    #pragma unroll
    for (int t=0;t<2;++t)
      #pragma unroll
      for (int i=0;i<4;++i){
        int gr = rowBase + wave*32 + t*16 + quad*4 + i;
        float v[NT]; float s=0.f, q=0.f;
        #pragma unroll
        for (int ct=0;ct<NT;++ct){
          v[ct] = acc[t][ct][i] + biasv[ct];
          s += v[ct]; q = fmaf(v[ct], v[ct], q);
        }
        #pragma unroll
        for (int off=1; off<16; off<<=1){ s += __shfl_xor(s,off); q += __shfl_xor(q,off); }
        float mean = s * (1.f/NCOL);
        float inv  = rsqrtf(q*(1.f/NCOL) - mean*mean + 1e-5f);
        if (gr < NN){
          #pragma unroll
          for (int ct=0;ct<NT;++ct)
            out[(size_t)gr*NCOL + ct*16 + l16] = fmaxf((v[ct]-mean)*inv*gv[ct] + bv[ct], 0.f);
        }
      }
  }
}

// ---------------- GAT aggregation (2 passes: max, then fused exp-sum+weighted) ----
__launch_bounds__(256)
__global__ void gat_aggregate_kernel(const float* __restrict__ xw, const float* __restrict__ es,
                                     const float* __restrict__ ed, const int* __restrict__ row_start,
                                     const int* __restrict__ csr_src, const float* __restrict__ bgat,
                                     float* __restrict__ out){
  int gid = blockIdx.x*256 + threadIdx.x;
  int n = gid >> 6, lane = gid & 63;
  if (n >= NN) return;
  int beg = row_start[n], end = row_start[n+1];
  float edn = ed[n];
  float sc_self = lrelu(es[n] + edn);
  float m = sc_self;
  for (int i = beg + lane; i < end; i += 64)
    m = fmaxf(m, lrelu(es[csr_src[i]] + edn));
  #pragma unroll
  for (int off=32; off; off>>=1) m = fmaxf(m, __shfl_xor(m, off));
  float wsum = __expf(sc_self - m);
  float a0 = wsum * xw[(size_t)n*HD + lane];
  float a1 = wsum * xw[(size_t)n*HD + 64 + lane];
  for (int i = beg; i < end; ++i){
    int s = csr_src[i];
    float w = __expf(lrelu(es[s] + edn) - m);
    wsum += w;
    a0 = fmaf(w, xw[(size_t)s*HD + lane], a0);
    a1 = fmaf(w, xw[(size_t)s*HD + 64 + lane], a1);
  }
  float dinv = 1.f/(wsum + 1e-16f);
  out[(size_t)n*HD + lane]      = a0*dinv + bgat[lane];
  out[(size_t)n*HD + 64 + lane] = a1*dinv + bgat[64+lane];
}

// ---------------- GraphNorm: per-group stats (batch sorted, no atomics) ----------
__launch_bounds__(256)
__global__ void gn_group_kernel(const float* __restrict__ x, const int* __restrict__ gstart,
                                const float* __restrict__ gnw, const float* __restrict__ gnms,
                                float* __restrict__ shiftv, float* __restrict__ scalev){
  int g = blockIdx.x;
  int n0 = gstart[g], n1 = gstart[g+1];
  int f = threadIdx.x & 127, half = threadIdx.x >> 7;
  float s = 0.f, q = 0.f;
  for (int n = n0 + half; n < n1; n += 2){
    float v = x[(size_t)n*HD + f];
    s += v; q = fmaf(v, v, q);
  }
  __shared__ float rs[256], rq[256];
  rs[threadIdx.x] = s; rq[threadIdx.x] = q;
  __syncthreads();
  if (threadIdx.x < 128){
    s = rs[threadIdx.x] + rs[threadIdx.x+128];
    q = rq[threadIdx.x] + rq[threadIdx.x+128];
    float c = fmaxf((float)(n1 - n0), 1.f);
    float mean = s / c;
    float ms = gnms[f];
    // var of (x - ms*mean) = E[x^2] - mean^2*ms*(2-ms)
    float var = q/c - mean*mean*ms*(2.f - ms);
    shiftv[g*HD+f] = ms*mean;
    scalev[g*HD+f] = gnw[f] / sqrtf(var + 1e-5f);
  }
}

template<bool RES>
__launch_bounds__(256)
__global__ void gn_norm_kernel(const float* __restrict__ x, const int* __restrict__ batch,
                               const float* __restrict__ shiftv, const float* __restrict__ scalev,
                               const float* __restrict__ gnb, const float* __restrict__ res,
                               float* __restrict__ out){
  int idx = blockIdx.x*256 + threadIdx.x;   // float4 index
  if (idx >= NN*32) return;
  int n = idx >> 5, c4 = idx & 31;
  int f = c4*4;
  int g = batch[n];
  float4 xv = *(const float4*)&x[(size_t)n*HD + f];
  float4 sh = *(const float4*)&shiftv[g*HD + f];
  float4 sc = *(const float4*)&scalev[g*HD + f];
  float4 bb = *(const float4*)&gnb[f];
  float4 v;
  v.x = fmaxf((xv.x - sh.x)*sc.x + bb.x, 0.f);
  v.y = fmaxf((xv.y - sh.y)*sc.y + bb.y, 0.f);
  v.z = fmaxf((xv.z - sh.z)*sc.z + bb.z, 0.f);
  v.w = fmaxf((xv.w - sh.w)*sc.w + bb.w, 0.f);
  if (RES){
    float4 r = *(const float4*)&res[(size_t)n*HD + f];
    v.x += r.x; v.y += r.y; v.z += r.z; v.w += r.w;
  }
  *(float4*)&out[(size_t)n*HD + f] = v;
}

// ---------------- fc2: [N,64]@[64,1] ----------------
__launch_bounds__(256)
__global__ void fc2_kernel(const float* __restrict__ x, const float* __restrict__ w,
                           const float* __restrict__ b, float* __restrict__ out){
  int gid = blockIdx.x*256 + threadIdx.x;
  int n = gid >> 6, lane = gid & 63;
  if (n >= NN) return;
  float v = x[(size_t)n*64 + lane] * w[lane];
  #pragma unroll
  for (int off=32; off; off>>=1) v += __shfl_down(v, off);
  if (lane == 0) out[n] = v + b[0];
}

// ---------------- launch ----------------
extern "C" void kernel_launch(void* const* d_in, const int* in_sizes, int n_in,
                              void* d_out, int out_size, void* d_ws, size_t ws_size,
                              hipStream_t stream){
  const float* rna    = (const float*)d_in[0];
  const float* ss     = (const float*)d_in[1];
  const int*   eidx   = (const int*)d_in[2];
  const int*   batch  = (const int*)d_in[3];
  const float* W_fuse = (const float*)d_in[4];
  const float* b_fuse = (const float*)d_in[5];
  const float* ln1_g  = (const float*)d_in[6];
  const float* ln1_b  = (const float*)d_in[7];
  const float* W_gat  = (const float*)d_in[8];
  const float* att_src= (const float*)d_in[9];
  const float* att_dst= (const float*)d_in[10];
  const float* b_gat  = (const float*)d_in[11];
  const float* gn_w   = (const float*)d_in[12];
  const float* gn_b   = (const float*)d_in[13];
  const float* gn_ms  = (const float*)d_in[14];
  const float* W_gate = (const float*)d_in[15];
  const float* b_gate = (const float*)d_in[16];
  const float* W_head = (const float*)d_in[17];
  const float* b_head = (const float*)d_in[18];
  const float* ln2_g  = (const float*)d_in[19];
  const float* ln2_b  = (const float*)d_in[20];
  const float* W_fc1  = (const float*)d_in[21];
  const float* b_fc1  = (const float*)d_in[22];
  const float* ln3_g  = (const float*)d_in[23];
  const float* ln3_b  = (const float*)d_in[24];
  const float* W_fc2  = (const float*)d_in[25];
  const float* b_fc2  = (const float*)d_in[26];
  float* outp = (float*)d_out;

  const int* srcl = eidx;
  const int* dstl = eidx + EE;

  char* base = (char*)d_ws;
  size_t off = 0;
  auto alloc = [&](size_t bytes)->void*{
    void* p = base + off; off = (off + bytes + 255) & ~(size_t)255; return p;
  };
  float* h    = (float*)alloc((size_t)NN*HD*4);
  float* h1   = (float*)alloc((size_t)NN*HD*4);
  float* h2   = (float*)alloc((size_t)NN*HD*4);
  float* xw   = (float*)alloc((size_t)NN*HD*4);
  float* y    = (float*)alloc((size_t)NN*HD*4);
  float* es   = (float*)alloc((size_t)NN*4);
  float* ed   = (float*)alloc((size_t)NN*4);
  float* shiftv = (float*)alloc(GG*HD*4);
  float* scalev = (float*)alloc(GG*HD*4);
  int* deg       = (int*)alloc((size_t)NN*4);
  int* row_start = (int*)alloc((size_t)(NN+1)*4);
  int* cursor    = (int*)alloc((size_t)NN*4);
  int* csr_src   = (int*)alloc((size_t)EE*4);
  int* blocksum  = (int*)alloc(256*4);
  int* gstart    = (int*)alloc((GG+1)*4);
  short* Wt_fuse = (short*)alloc((size_t)128*704*2);
  short* Wt_gat  = (short*)alloc((size_t)128*128*2);
  short* Wt_gate = (short*)alloc((size_t)128*256*2);
  short* Wt_head = (short*)alloc((size_t)128*128*2);
  short* Wt_fc1  = (short*)alloc((size_t)64*128*2);
  float* hg = xw;   // reuse
  float* t1 = y;    // reuse
  float* t2 = h;    // reuse

  const int NB  = (NN + 255)/256;
  const int GB  = (NN + 127)/128;          // 391 blocks, 128 rows each
  const int EB  = (EE + 255)/256;
  const int WVB = (NN*64 + 255)/256;

  // weight prep (bf16, transposed, zero-padded K)
  wprep_kernel<<<(128*704+255)/256, 256, 0, stream>>>(W_fuse, Wt_fuse, KFUSE, 128, 704);
  wprep_kernel<<<(128*128+255)/256, 256, 0, stream>>>(W_gat,  Wt_gat,  128, 128, 128);
  wprep_kernel<<<(128*256+255)/256, 256, 0, stream>>>(W_gate, Wt_gate, 256, 128, 256);
  wprep_kernel<<<(128*128+255)/256, 256, 0, stream>>>(W_head, Wt_head, 128, 128, 128);
  wprep_kernel<<<( 64*128+255)/256, 256, 0, stream>>>(W_fc1,  Wt_fc1,  128,  64, 128);

  // graph prep
  hipMemsetAsync(deg, 0, (size_t)NN*4, stream);
  hist_dst_kernel<<<EB, 256, 0, stream>>>(dstl, deg);
  scan1_kernel<<<NB, 256, 0, stream>>>(deg, row_start, blocksum);
  scan2_kernel<<<1, 256, 0, stream>>>(blocksum, NB);
  scan3_kernel<<<NB, 256, 0, stream>>>(row_start, blocksum, cursor);
  scatter_kernel<<<EB, 256, 0, stream>>>(srcl, dstl, cursor, csr_src);
  gstart_kernel<<<NB, 256, 0, stream>>>(batch, gstart);

  // fuse + LN1 + relu -> h
  mfma_gemm<0,8><<<GB, 256, 0, stream>>>(rna, ss, Wt_fuse, b_fuse, ln1_g, ln1_b,
                                         nullptr, nullptr, h, nullptr, nullptr, KFUSE, 704);
  // ---- GAT layer 1 ----
  mfma_gemm<1,8><<<GB, 256, 0, stream>>>(h, nullptr, Wt_gat, nullptr, nullptr, nullptr,
                                         att_src, att_dst, xw, es, ed, HD, HD);
  gat_aggregate_kernel<<<WVB, 256, 0, stream>>>(xw, es, ed, row_start, csr_src, b_gat, y);
  gn_group_kernel<<<GG, 256, 0, stream>>>(y, gstart, gn_w, gn_ms, shiftv, scalev);
  gn_norm_kernel<false><<<(NN*32+255)/256, 256, 0, stream>>>(y, batch, shiftv, scalev, gn_b, nullptr, h1);

  // ---- GAT layer 2 ----
  mfma_gemm<1,8><<<GB, 256, 0, stream>>>(h1, nullptr, Wt_gat, nullptr, nullptr, nullptr,
                                         att_src, att_dst, xw, es, ed, HD, HD);
  gat_aggregate_kernel<<<WVB, 256, 0, stream>>>(xw, es, ed, row_start, csr_src, b_gat, y);
  gn_group_kernel<<<GG, 256, 0, stream>>>(y, gstart, gn_w, gn_ms, shiftv, scalev);
  gn_norm_kernel<true><<<(NN*32+255)/256, 256, 0, stream>>>(y, batch, shiftv, scalev, gn_b, h, h2);

  // gate combine -> hg (reuses xw)
  mfma_gemm<2,8><<<GB, 256, 0, stream>>>(h1, h2, Wt_gate, b_gate, nullptr, nullptr,
                                         nullptr, nullptr, hg, nullptr, nullptr, 256, 256);
  // head + LN2 + relu -> t1 (reuses y)
  mfma_gemm<3,8><<<GB, 256, 0, stream>>>(hg, nullptr, Wt_head, b_head, ln2_g, ln2_b,
                                         nullptr, nullptr, t1, nullptr, nullptr, HD, HD);
  // fc1 + LN3 + relu -> t2 (reuses h)
  mfma_gemm<4,4><<<GB, 256, 0, stream>>>(t1, nullptr, Wt_fc1, b_fc1, ln3_g, ln3_b,
                                         nullptr, nullptr, t2, nullptr, nullptr, HD, HD);
  // fc2 -> out
  fc2_kernel<<<WVB, 256, 0, stream>>>(t2, W_fc2, b_fc2, outp);
}

// Round 4
// 763.029 us; speedup vs baseline: 1.7292x; 1.2381x over previous
//
#include <hip/hip_runtime.h>
#include <hip/hip_bf16.h>
#include <math.h>

#define NN 50000
#define EE 800000
#define RNA_D 645
#define KFUSE 651
#define KPACK 704   // padded K for packed bf16 input (multiple of 64)
#define HD 128
#define GG 200
#define SAK 72   // LDS k-stride (bf16 elems): 64 + 8 pad, 144B rows (16B-aligned, bank-spread)

typedef __attribute__((ext_vector_type(8))) short shortx8;
typedef __attribute__((ext_vector_type(4))) float floatx4;

__device__ __forceinline__ float lrelu(float x){ return x >= 0.f ? x : 0.2f*x; }
__device__ __forceinline__ short f2bf(float x){
  union { __hip_bfloat16 h; short s; } u; u.h = __float2bfloat16(x); return u.s;
}

// ---------------- input pack: concat(rna,ss) -> bf16 [NN][KPACK], coalesced ----
__launch_bounds__(256)
__global__ void pack_kernel(const float* __restrict__ rna, const float* __restrict__ ss,
                            short* __restrict__ Abf){
  // 2 rows per block, 128 threads per row
  int row = blockIdx.x*2 + (threadIdx.x >> 7);
  int t = threadIdx.x & 127;
  if (row >= NN) return;
  const float* rrow = rna + (size_t)row*RNA_D;
  short* orow = Abf + (size_t)row*KPACK;
  #pragma unroll
  for (int j=0;j<6;++j){
    int c = t + j*128;
    if (c < KPACK){
      float v = 0.f;
      if (c < RNA_D) v = rrow[c];
      else if (c < KFUSE) v = ss[row*6 + (c - RNA_D)];
      orow[c] = f2bf(v);
    }
  }
}

// ---------------- graph prep ----------------
__global__ void hist_dst_kernel(const int* __restrict__ dst, int* __restrict__ deg){
  int e = blockIdx.x*256 + threadIdx.x;
  if (e < EE) atomicAdd(&deg[dst[e]], 1);
}
__global__ void scan1_kernel(const int* __restrict__ deg, int* __restrict__ row_start,
                             int* __restrict__ blocksum){
  __shared__ int s[256];
  int i = blockIdx.x*256 + threadIdx.x;
  int v = (i < NN) ? deg[i] : 0;
  s[threadIdx.x] = v;
  __syncthreads();
  for (int off=1; off<256; off<<=1){
    int t = (threadIdx.x >= off) ? s[threadIdx.x-off] : 0;
    __syncthreads();
    s[threadIdx.x] += t;
    __syncthreads();
  }
  if (i < NN) row_start[i] = s[threadIdx.x] - v;
  if (threadIdx.x == 255) blocksum[blockIdx.x] = s[255];
}
__global__ void scan2_kernel(int* __restrict__ blocksum, int nb){
  __shared__ int s[256];
  int v = (threadIdx.x < nb) ? blocksum[threadIdx.x] : 0;
  s[threadIdx.x] = v;
  __syncthreads();
  for (int off=1; off<256; off<<=1){
    int t = (threadIdx.x >= off) ? s[threadIdx.x-off] : 0;
    __syncthreads();
    s[threadIdx.x] += t;
    __syncthreads();
  }
  blocksum[threadIdx.x] = s[threadIdx.x] - v;
}
__global__ void scan3_kernel(int* __restrict__ row_start, const int* __restrict__ blocksum,
                             int* __restrict__ cursor){
  int i = blockIdx.x*256 + threadIdx.x;
  if (i < NN){
    int v = row_start[i] + blocksum[blockIdx.x];
    row_start[i] = v;
    cursor[i] = v;
  }
  if (i == 0) row_start[NN] = EE;
}
__global__ void scatter_kernel(const int* __restrict__ srcl, const int* __restrict__ dstl,
                               int* __restrict__ cursor, int* __restrict__ csr_src){
  int e = blockIdx.x*256 + threadIdx.x;
  if (e >= EE) return;
  int d = dstl[e];
  int slot = atomicAdd(&cursor[d], 1);
  csr_src[slot] = srcl[e];
}
__global__ void gstart_kernel(const int* __restrict__ batch, int* __restrict__ gstart){
  int n = blockIdx.x*256 + threadIdx.x;
  if (n >= NN) return;
  int g = batch[n];
  if (n == 0){ for (int gg=0; gg<=g; ++gg) gstart[gg] = 0; }
  else { int gp = batch[n-1]; for (int gg=gp+1; gg<=g; ++gg) gstart[gg] = n; }
  if (n == NN-1){ for (int gg=g+1; gg<=GG; ++gg) gstart[gg] = NN; }
}

// ---------------- weight prep: W[K][N] fp32 -> Wt[N][Kp] bf16 (zero-padded) ----
__global__ void wprep_kernel(const float* __restrict__ W, short* __restrict__ Wt,
                             int K, int N, int Kp){
  int idx = blockIdx.x*256 + threadIdx.x;
  if (idx >= N*Kp) return;
  int n = idx / Kp, k = idx - n*Kp;
  float v = (k < K) ? W[k*N + n] : 0.f;
  Wt[idx] = f2bf(v);
}

// ---------------- MFMA GEMM ----------------
// 128 rows x (NT*16) cols per block, 256 threads = 4 waves.
// MODE 0: fuse   A=packed bf16 (stride KPACK) K=704  epi: +bias, LN(128), relu
// MODE 1: xw     A stride 128 fp32  K=128  epi: store + es/ed (fused edge-score proj)
// MODE 2: gate   A=h1|h2 fp32       K=256  epi: sigmoid(+bias) combine h1/h2
// MODE 3: head   A stride 128 fp32  K=128  epi: +bias, LN(128), relu
// MODE 4: fc1    A stride 128 fp32  K=128  epi: +bias, LN(64), relu   (NT=4)
template<int MODE, int NT>
__launch_bounds__(256)
__global__ void mfma_gemm(const float* __restrict__ A0, const float* __restrict__ A1,
                          const short* __restrict__ Apk,
                          const short* __restrict__ Wt, const float* __restrict__ bias,
                          const float* __restrict__ gw, const float* __restrict__ gb,
                          const float* __restrict__ as_, const float* __restrict__ ad_,
                          float* __restrict__ out, float* __restrict__ es, float* __restrict__ ed,
                          int K, int Kp){
  __shared__ short sA[128*SAK];
  __shared__ short sB[NT*16*SAK];
  const int tid  = threadIdx.x;
  const int wave = tid >> 6, lane = tid & 63;
  const int quad = lane >> 4, l16 = lane & 15;
  const int rowBase = blockIdx.x * 128;
  const int NCOL = NT*16;

  floatx4 acc[2][NT];
  #pragma unroll
  for (int t=0;t<2;++t)
    #pragma unroll
    for (int ct=0;ct<NT;++ct)
      #pragma unroll
      for (int j=0;j<4;++j) acc[t][ct][j] = 0.f;

  const int srow = tid >> 1, shalf = tid & 1;
  const int sgr = rowBase + srow;

  for (int k0 = 0; k0 < K; k0 += 64){
    // ---- stage A ----
    if (MODE == 0){
      // packed bf16, 16B-aligned rows: shortx8 vector loads, coalesced
      #pragma unroll
      for (int j=0;j<4;++j){
        int flat = tid + j*256;          // 1024 shortx8 chunks = 128 rows x 8 chunks
        int r = flat >> 3, c8 = flat & 7;
        int gr = rowBase + r;
        shortx8 v = {0,0,0,0,0,0,0,0};
        if (gr < NN) v = *(const shortx8*)&Apk[(size_t)gr*KPACK + k0 + c8*8];
        *(shortx8*)&sA[r*SAK + c8*8] = v;
      }
    } else {
      int kb = k0 + shalf*32;
      short tmp[32];
      const float* p;
      if (MODE == 2) p = (kb < HD) ? (A0 + (size_t)sgr*HD + kb) : (A1 + (size_t)sgr*HD + (kb - HD));
      else           p = A0 + (size_t)sgr*HD + kb;
      #pragma unroll
      for (int q4=0;q4<8;++q4){
        float4 f = (sgr < NN) ? *(const float4*)(p + q4*4) : make_float4(0.f,0.f,0.f,0.f);
        tmp[q4*4+0] = f2bf(f.x); tmp[q4*4+1] = f2bf(f.y);
        tmp[q4*4+2] = f2bf(f.z); tmp[q4*4+3] = f2bf(f.w);
      }
      #pragma unroll
      for (int q8=0;q8<4;++q8)
        *(shortx8*)&sA[srow*SAK + shalf*32 + q8*8] = *(shortx8*)&tmp[q8*8];
    }
    // ---- stage B (bf16, [n][k] layout) ----
    if (NT == 8){
      int col = tid >> 1, kb = k0 + (tid&1)*32;
      #pragma unroll
      for (int q8=0;q8<4;++q8)
        *(shortx8*)&sB[col*SAK + (tid&1)*32 + q8*8] = *(const shortx8*)&Wt[(size_t)col*Kp + kb + q8*8];
    } else {
      if (tid < NT*32){
        int col = tid >> 1, kb = k0 + (tid&1)*32;
        #pragma unroll
        for (int q8=0;q8<4;++q8)
          *(shortx8*)&sB[col*SAK + (tid&1)*32 + q8*8] = *(const shortx8*)&Wt[(size_t)col*Kp + kb + q8*8];
      }
    }
    __syncthreads();
    // ---- MFMA ----
    #pragma unroll
    for (int ks=0; ks<2; ++ks){
      int kb = ks*32 + quad*8;
      shortx8 af0 = *(const shortx8*)&sA[(wave*32 +      l16)*SAK + kb];
      shortx8 af1 = *(const shortx8*)&sA[(wave*32 + 16 + l16)*SAK + kb];
      #pragma unroll
      for (int ct=0; ct<NT; ++ct){
        shortx8 bf = *(const shortx8*)&sB[(ct*16 + l16)*SAK + kb];
        acc[0][ct] = __builtin_amdgcn_mfma_f32_16x16x32_bf16(af0, bf, acc[0][ct], 0,0,0);
        acc[1][ct] = __builtin_amdgcn_mfma_f32_16x16x32_bf16(af1, bf, acc[1][ct], 0,0,0);
      }
    }
    __syncthreads();
  }

  // ---- epilogue ----
  if (MODE == 1){
    float asv[NT], adv[NT];
    #pragma unroll
    for (int ct=0;ct<NT;++ct){ asv[ct] = as_[ct*16+l16]; adv[ct] = ad_[ct*16+l16]; }
    #pragma unroll
    for (int t=0;t<2;++t)
      #pragma unroll
      for (int i=0;i<4;++i){
        int gr = rowBase + wave*32 + t*16 + quad*4 + i;
        float s=0.f, d=0.f;
        #pragma unroll
        for (int ct=0;ct<NT;++ct){
          float v = acc[t][ct][i];
          s = fmaf(v, asv[ct], s); d = fmaf(v, adv[ct], d);
          if (gr < NN) out[(size_t)gr*HD + ct*16 + l16] = v;
        }
        #pragma unroll
        for (int off=1; off<16; off<<=1){ s += __shfl_xor(s,off); d += __shfl_xor(d,off); }
        if (l16 == 0 && gr < NN){ es[gr] = s; ed[gr] = d; }
      }
  } else if (MODE == 2){
    float biasv[NT];
    #pragma unroll
    for (int ct=0;ct<NT;++ct) biasv[ct] = bias[ct*16+l16];
    #pragma unroll
    for (int t=0;t<2;++t)
      #pragma unroll
      for (int i=0;i<4;++i){
        int gr = rowBase + wave*32 + t*16 + quad*4 + i;
        if (gr < NN){
          #pragma unroll
          for (int ct=0;ct<NT;++ct){
            int c = ct*16 + l16;
            float g = 1.f/(1.f + __expf(-(acc[t][ct][i] + biasv[ct])));
            float x1 = A0[(size_t)gr*HD + c];
            float x2 = A1[(size_t)gr*HD + c];
            out[(size_t)gr*HD + c] = g*x1 + (1.f-g)*x2;
          }
        }
      }
  } else { // MODE 0 / 3 / 4 : +bias, LN(NCOL), relu
    float biasv[NT], gv[NT], bv[NT];
    #pragma unroll
    for (int ct=0;ct<NT;++ct){
      biasv[ct] = bias[ct*16+l16]; gv[ct] = gw[ct*16+l16]; bv[ct] = gb[ct*16+l16];
    }
    #pragma unroll
    for (int t=0;t<2;++t)
      #pragma unroll
      for (int i=0;i<4;++i){
        int gr = rowBase + wave*32 + t*16 + quad*4 + i;
        float v[NT]; float s=0.f, q=0.f;
        #pragma unroll
        for (int ct=0;ct<NT;++ct){
          v[ct] = acc[t][ct][i] + biasv[ct];
          s += v[ct]; q = fmaf(v[ct], v[ct], q);
        }
        #pragma unroll
        for (int off=1; off<16; off<<=1){ s += __shfl_xor(s,off); q += __shfl_xor(q,off); }
        float mean = s * (1.f/NCOL);
        float inv  = rsqrtf(q*(1.f/NCOL) - mean*mean + 1e-5f);
        if (gr < NN){
          #pragma unroll
          for (int ct=0;ct<NT;++ct)
            out[(size_t)gr*NCOL + ct*16 + l16] = fmaxf((v[ct]-mean)*inv*gv[ct] + bv[ct], 0.f);
        }
      }
  }
}

// ---------------- GAT aggregation ----------------
__launch_bounds__(256)
__global__ void gat_aggregate_kernel(const float* __restrict__ xw, const float* __restrict__ es,
                                     const float* __restrict__ ed, const int* __restrict__ row_start,
                                     const int* __restrict__ csr_src, const float* __restrict__ bgat,
                                     float* __restrict__ out){
  int gid = blockIdx.x*256 + threadIdx.x;
  int n = gid >> 6, lane = gid & 63;
  if (n >= NN) return;
  int beg = row_start[n], end = row_start[n+1];
  float edn = ed[n];
  float sc_self = lrelu(es[n] + edn);
  float m = sc_self;
  for (int i = beg + lane; i < end; i += 64)
    m = fmaxf(m, lrelu(es[csr_src[i]] + edn));
  #pragma unroll
  for (int off=32; off; off>>=1) m = fmaxf(m, __shfl_xor(m, off));
  float wsum = __expf(sc_self - m);
  float a0 = wsum * xw[(size_t)n*HD + lane];
  float a1 = wsum * xw[(size_t)n*HD + 64 + lane];
  for (int i = beg; i < end; ++i){
    int s = csr_src[i];
    float w = __expf(lrelu(es[s] + edn) - m);
    wsum += w;
    a0 = fmaf(w, xw[(size_t)s*HD + lane], a0);
    a1 = fmaf(w, xw[(size_t)s*HD + 64 + lane], a1);
  }
  float dinv = 1.f/(wsum + 1e-16f);
  out[(size_t)n*HD + lane]      = a0*dinv + bgat[lane];
  out[(size_t)n*HD + 64 + lane] = a1*dinv + bgat[64+lane];
}

// ---------------- GraphNorm: per-group stats (batch sorted, no atomics) ----------
__launch_bounds__(256)
__global__ void gn_group_kernel(const float* __restrict__ x, const int* __restrict__ gstart,
                                const float* __restrict__ gnw, const float* __restrict__ gnms,
                                float* __restrict__ shiftv, float* __restrict__ scalev){
  int g = blockIdx.x;
  int n0 = gstart[g], n1 = gstart[g+1];
  int f = threadIdx.x & 127, half = threadIdx.x >> 7;
  float s = 0.f, q = 0.f;
  for (int n = n0 + half; n < n1; n += 2){
    float v = x[(size_t)n*HD + f];
    s += v; q = fmaf(v, v, q);
  }
  __shared__ float rs[256], rq[256];
  rs[threadIdx.x] = s; rq[threadIdx.x] = q;
  __syncthreads();
  if (threadIdx.x < 128){
    s = rs[threadIdx.x] + rs[threadIdx.x+128];
    q = rq[threadIdx.x] + rq[threadIdx.x+128];
    float c = fmaxf((float)(n1 - n0), 1.f);
    float mean = s / c;
    float ms = gnms[f];
    float var = q/c - mean*mean*ms*(2.f - ms);
    shiftv[g*HD+f] = ms*mean;
    scalev[g*HD+f] = gnw[f] / sqrtf(var + 1e-5f);
  }
}

template<bool RES>
__launch_bounds__(256)
__global__ void gn_norm_kernel(const float* __restrict__ x, const int* __restrict__ batch,
                               const float* __restrict__ shiftv, const float* __restrict__ scalev,
                               const float* __restrict__ gnb, const float* __restrict__ res,
                               float* __restrict__ out){
  int idx = blockIdx.x*256 + threadIdx.x;   // float4 index
  if (idx >= NN*32) return;
  int n = idx >> 5, c4 = idx & 31;
  int f = c4*4;
  int g = batch[n];
  float4 xv = *(const float4*)&x[(size_t)n*HD + f];
  float4 sh = *(const float4*)&shiftv[g*HD + f];
  float4 sc = *(const float4*)&scalev[g*HD + f];
  float4 bb = *(const float4*)&gnb[f];
  float4 v;
  v.x = fmaxf((xv.x - sh.x)*sc.x + bb.x, 0.f);
  v.y = fmaxf((xv.y - sh.y)*sc.y + bb.y, 0.f);
  v.z = fmaxf((xv.z - sh.z)*sc.z + bb.z, 0.f);
  v.w = fmaxf((xv.w - sh.w)*sc.w + bb.w, 0.f);
  if (RES){
    float4 r = *(const float4*)&res[(size_t)n*HD + f];
    v.x += r.x; v.y += r.y; v.z += r.z; v.w += r.w;
  }
  *(float4*)&out[(size_t)n*HD + f] = v;
}

// ---------------- fc2: [N,64]@[64,1] ----------------
__launch_bounds__(256)
__global__ void fc2_kernel(const float* __restrict__ x, const float* __restrict__ w,
                           const float* __restrict__ b, float* __restrict__ out){
  int gid = blockIdx.x*256 + threadIdx.x;
  int n = gid >> 6, lane = gid & 63;
  if (n >= NN) return;
  float v = x[(size_t)n*64 + lane] * w[lane];
  #pragma unroll
  for (int off=32; off; off>>=1) v += __shfl_down(v, off);
  if (lane == 0) out[n] = v + b[0];
}

// ---------------- launch ----------------
extern "C" void kernel_launch(void* const* d_in, const int* in_sizes, int n_in,
                              void* d_out, int out_size, void* d_ws, size_t ws_size,
                              hipStream_t stream){
  const float* rna    = (const float*)d_in[0];
  const float* ss     = (const float*)d_in[1];
  const int*   eidx   = (const int*)d_in[2];
  const int*   batch  = (const int*)d_in[3];
  const float* W_fuse = (const float*)d_in[4];
  const float* b_fuse = (const float*)d_in[5];
  const float* ln1_g  = (const float*)d_in[6];
  const float* ln1_b  = (const float*)d_in[7];
  const float* W_gat  = (const float*)d_in[8];
  const float* att_src= (const float*)d_in[9];
  const float* att_dst= (const float*)d_in[10];
  const float* b_gat  = (const float*)d_in[11];
  const float* gn_w   = (const float*)d_in[12];
  const float* gn_b   = (const float*)d_in[13];
  const float* gn_ms  = (const float*)d_in[14];
  const float* W_gate = (const float*)d_in[15];
  const float* b_gate = (const float*)d_in[16];
  const float* W_head = (const float*)d_in[17];
  const float* b_head = (const float*)d_in[18];
  const float* ln2_g  = (const float*)d_in[19];
  const float* ln2_b  = (const float*)d_in[20];
  const float* W_fc1  = (const float*)d_in[21];
  const float* b_fc1  = (const float*)d_in[22];
  const float* ln3_g  = (const float*)d_in[23];
  const float* ln3_b  = (const float*)d_in[24];
  const float* W_fc2  = (const float*)d_in[25];
  const float* b_fc2  = (const float*)d_in[26];
  float* outp = (float*)d_out;

  const int* srcl = eidx;
  const int* dstl = eidx + EE;

  char* base = (char*)d_ws;
  size_t off = 0;
  auto alloc = [&](size_t bytes)->void*{
    void* p = base + off; off = (off + bytes + 255) & ~(size_t)255; return p;
  };
  float* h    = (float*)alloc((size_t)NN*HD*4);
  float* h1   = (float*)alloc((size_t)NN*HD*4);
  float* h2   = (float*)alloc((size_t)NN*HD*4);
  float* xw   = (float*)alloc((size_t)NN*HD*4);
  float* y    = (float*)alloc((size_t)NN*HD*4);
  float* es   = (float*)alloc((size_t)NN*4);
  float* ed   = (float*)alloc((size_t)NN*4);
  float* shiftv = (float*)alloc(GG*HD*4);
  float* scalev = (float*)alloc(GG*HD*4);
  int* deg       = (int*)alloc((size_t)NN*4);
  int* row_start = (int*)alloc((size_t)(NN+1)*4);
  int* cursor    = (int*)alloc((size_t)NN*4);
  int* csr_src   = (int*)alloc((size_t)EE*4);
  int* blocksum  = (int*)alloc(256*4);
  int* gstart    = (int*)alloc((GG+1)*4);
  short* Abf     = (short*)alloc((size_t)NN*KPACK*2);
  short* Wt_fuse = (short*)alloc((size_t)128*KPACK*2);
  short* Wt_gat  = (short*)alloc((size_t)128*128*2);
  short* Wt_gate = (short*)alloc((size_t)128*256*2);
  short* Wt_head = (short*)alloc((size_t)128*128*2);
  short* Wt_fc1  = (short*)alloc((size_t)64*128*2);
  float* hg = xw;   // reuse
  float* t1 = y;    // reuse
  float* t2 = h;    // reuse

  const int NB  = (NN + 255)/256;
  const int GB  = (NN + 127)/128;          // 391 blocks, 128 rows each
  const int EB  = (EE + 255)/256;
  const int WVB = (NN*64 + 255)/256;

  // input pack (coalesced fp32 -> aligned bf16)
  pack_kernel<<<(NN+1)/2, 256, 0, stream>>>(rna, ss, Abf);

  // weight prep (bf16, transposed, zero-padded K)
  wprep_kernel<<<(128*KPACK+255)/256, 256, 0, stream>>>(W_fuse, Wt_fuse, KFUSE, 128, KPACK);
  wprep_kernel<<<(128*128+255)/256, 256, 0, stream>>>(W_gat,  Wt_gat,  128, 128, 128);
  wprep_kernel<<<(128*256+255)/256, 256, 0, stream>>>(W_gate, Wt_gate, 256, 128, 256);
  wprep_kernel<<<(128*128+255)/256, 256, 0, stream>>>(W_head, Wt_head, 128, 128, 128);
  wprep_kernel<<<( 64*128+255)/256, 256, 0, stream>>>(W_fc1,  Wt_fc1,  128,  64, 128);

  // graph prep
  hipMemsetAsync(deg, 0, (size_t)NN*4, stream);
  hist_dst_kernel<<<EB, 256, 0, stream>>>(dstl, deg);
  scan1_kernel<<<NB, 256, 0, stream>>>(deg, row_start, blocksum);
  scan2_kernel<<<1, 256, 0, stream>>>(blocksum, NB);
  scan3_kernel<<<NB, 256, 0, stream>>>(row_start, blocksum, cursor);
  scatter_kernel<<<EB, 256, 0, stream>>>(srcl, dstl, cursor, csr_src);
  gstart_kernel<<<NB, 256, 0, stream>>>(batch, gstart);

  // fuse + LN1 + relu -> h
  mfma_gemm<0,8><<<GB, 256, 0, stream>>>(nullptr, nullptr, Abf, Wt_fuse, b_fuse, ln1_g, ln1_b,
                                         nullptr, nullptr, h, nullptr, nullptr, KPACK, KPACK);
  // ---- GAT layer 1 ----
  mfma_gemm<1,8><<<GB, 256, 0, stream>>>(h, nullptr, nullptr, Wt_gat, nullptr, nullptr, nullptr,
                                         att_src, att_dst, xw, es, ed, HD, HD);
  gat_aggregate_kernel<<<WVB, 256, 0, stream>>>(xw, es, ed, row_start, csr_src, b_gat, y);
  gn_group_kernel<<<GG, 256, 0, stream>>>(y, gstart, gn_w, gn_ms, shiftv, scalev);
  gn_norm_kernel<false><<<(NN*32+255)/256, 256, 0, stream>>>(y, batch, shiftv, scalev, gn_b, nullptr, h1);

  // ---- GAT layer 2 ----
  mfma_gemm<1,8><<<GB, 256, 0, stream>>>(h1, nullptr, nullptr, Wt_gat, nullptr, nullptr, nullptr,
                                         att_src, att_dst, xw, es, ed, HD, HD);
  gat_aggregate_kernel<<<WVB, 256, 0, stream>>>(xw, es, ed, row_start, csr_src, b_gat, y);
  gn_group_kernel<<<GG, 256, 0, stream>>>(y, gstart, gn_w, gn_ms, shiftv, scalev);
  gn_norm_kernel<true><<<(NN*32+255)/256, 256, 0, stream>>>(y, batch, shiftv, scalev, gn_b, h, h2);

  // gate combine -> hg (reuses xw)
  mfma_gemm<2,8><<<GB, 256, 0, stream>>>(h1, h2, nullptr, Wt_gate, b_gate, nullptr, nullptr,
                                         nullptr, nullptr, hg, nullptr, nullptr, 256, 256);
  // head + LN2 + relu -> t1 (reuses y)
  mfma_gemm<3,8><<<GB, 256, 0, stream>>>(hg, nullptr, nullptr, Wt_head, b_head, ln2_g, ln2_b,
                                         nullptr, nullptr, t1, nullptr, nullptr, HD, HD);
  // fc1 + LN3 + relu -> t2 (reuses h)
  mfma_gemm<4,4><<<GB, 256, 0, stream>>>(t1, nullptr, nullptr, Wt_fc1, b_fc1, ln3_g, ln3_b,
                                         nullptr, nullptr, t2, nullptr, nullptr, HD, HD);
  // fc2 -> out
  fc2_kernel<<<WVB, 256, 0, stream>>>(t2, W_fc2, b_fc2, outp);
}

// Round 5
// 694.155 us; speedup vs baseline: 1.9008x; 1.0992x over previous
//
#include <hip/hip_runtime.h>
#include <hip/hip_bf16.h>
#include <math.h>

#define NN 50000
#define EE 800000
#define RNA_D 645
#define KFUSE 651
#define KPACK 704   // padded K for packed bf16 input (multiple of 64)
#define HD 128
#define GG 200
#define SAK 72   // LDS k-stride (bf16 elems): 64 + 8 pad

typedef __attribute__((ext_vector_type(8))) short shortx8;
typedef __attribute__((ext_vector_type(4))) float floatx4;

__device__ __forceinline__ float lrelu(float x){ return x >= 0.f ? x : 0.2f*x; }
__device__ __forceinline__ short f2bf(float x){
  union { __hip_bfloat16 h; short s; } u; u.h = __float2bfloat16(x); return u.s;
}

// ---------------- input pack: concat(rna,ss) -> bf16 [NN][KPACK], coalesced ----
__launch_bounds__(256)
__global__ void pack_kernel(const float* __restrict__ rna, const float* __restrict__ ss,
                            short* __restrict__ Abf){
  int row = blockIdx.x*2 + (threadIdx.x >> 7);
  int t = threadIdx.x & 127;
  if (row >= NN) return;
  const float* rrow = rna + (size_t)row*RNA_D;
  short* orow = Abf + (size_t)row*KPACK;
  #pragma unroll
  for (int j=0;j<6;++j){
    int c = t + j*128;
    if (c < KPACK){
      float v = 0.f;
      if (c < RNA_D) v = rrow[c];
      else if (c < KFUSE) v = ss[row*6 + (c - RNA_D)];
      orow[c] = f2bf(v);
    }
  }
}

// ---------------- graph prep ----------------
__global__ void hist_dst_kernel(const int* __restrict__ dst, int* __restrict__ deg){
  int e = blockIdx.x*256 + threadIdx.x;
  if (e < EE) atomicAdd(&deg[dst[e]], 1);
}
__global__ void scan1_kernel(const int* __restrict__ deg, int* __restrict__ row_start,
                             int* __restrict__ blocksum){
  __shared__ int s[256];
  int i = blockIdx.x*256 + threadIdx.x;
  int v = (i < NN) ? deg[i] : 0;
  s[threadIdx.x] = v;
  __syncthreads();
  for (int off=1; off<256; off<<=1){
    int t = (threadIdx.x >= off) ? s[threadIdx.x-off] : 0;
    __syncthreads();
    s[threadIdx.x] += t;
    __syncthreads();
  }
  if (i < NN) row_start[i] = s[threadIdx.x] - v;
  if (threadIdx.x == 255) blocksum[blockIdx.x] = s[255];
}
__global__ void scan2_kernel(int* __restrict__ blocksum, int nb){
  __shared__ int s[256];
  int v = (threadIdx.x < nb) ? blocksum[threadIdx.x] : 0;
  s[threadIdx.x] = v;
  __syncthreads();
  for (int off=1; off<256; off<<=1){
    int t = (threadIdx.x >= off) ? s[threadIdx.x-off] : 0;
    __syncthreads();
    s[threadIdx.x] += t;
    __syncthreads();
  }
  blocksum[threadIdx.x] = s[threadIdx.x] - v;
}
__global__ void scan3_kernel(int* __restrict__ row_start, const int* __restrict__ blocksum,
                             int* __restrict__ cursor){
  int i = blockIdx.x*256 + threadIdx.x;
  if (i < NN){
    int v = row_start[i] + blocksum[blockIdx.x];
    row_start[i] = v;
    cursor[i] = v;
  }
  if (i == 0) row_start[NN] = EE;
}
__global__ void scatter_kernel(const int* __restrict__ srcl, const int* __restrict__ dstl,
                               int* __restrict__ cursor, int* __restrict__ csr_src){
  int e = blockIdx.x*256 + threadIdx.x;
  if (e >= EE) return;
  int d = dstl[e];
  int slot = atomicAdd(&cursor[d], 1);
  csr_src[slot] = srcl[e];
}
__global__ void gstart_kernel(const int* __restrict__ batch, int* __restrict__ gstart){
  int n = blockIdx.x*256 + threadIdx.x;
  if (n >= NN) return;
  int g = batch[n];
  if (n == 0){ for (int gg=0; gg<=g; ++gg) gstart[gg] = 0; }
  else { int gp = batch[n-1]; for (int gg=gp+1; gg<=g; ++gg) gstart[gg] = n; }
  if (n == NN-1){ for (int gg=g+1; gg<=GG; ++gg) gstart[gg] = NN; }
}

// ---------------- weight prep: W[K][N] fp32 -> Wt[N][Kp] bf16 (zero-padded) ----
__global__ void wprep_kernel(const float* __restrict__ W, short* __restrict__ Wt,
                             int K, int N, int Kp){
  int idx = blockIdx.x*256 + threadIdx.x;
  if (idx >= N*Kp) return;
  int n = idx / Kp, k = idx - n*Kp;
  float v = (k < K) ? W[k*N + n] : 0.f;
  Wt[idx] = f2bf(v);
}

// ---------------- MFMA GEMM ----------------
template<int MODE, int NT>
__launch_bounds__(256)
__global__ void mfma_gemm(const float* __restrict__ A0, const float* __restrict__ A1,
                          const short* __restrict__ Apk,
                          const short* __restrict__ Wt, const float* __restrict__ bias,
                          const float* __restrict__ gw, const float* __restrict__ gb,
                          const float* __restrict__ as_, const float* __restrict__ ad_,
                          float* __restrict__ out, float* __restrict__ es, float* __restrict__ ed,
                          int K, int Kp){
  __shared__ short sA[128*SAK];
  __shared__ short sB[NT*16*SAK];
  const int tid  = threadIdx.x;
  const int wave = tid >> 6, lane = tid & 63;
  const int quad = lane >> 4, l16 = lane & 15;
  const int rowBase = blockIdx.x * 128;
  const int NCOL = NT*16;

  floatx4 acc[2][NT];
  #pragma unroll
  for (int t=0;t<2;++t)
    #pragma unroll
    for (int ct=0;ct<NT;++ct)
      #pragma unroll
      for (int j=0;j<4;++j) acc[t][ct][j] = 0.f;

  const int srow = tid >> 1, shalf = tid & 1;
  const int sgr = rowBase + srow;

  for (int k0 = 0; k0 < K; k0 += 64){
    // ---- stage A ----
    if (MODE == 0){
      #pragma unroll
      for (int j=0;j<4;++j){
        int flat = tid + j*256;
        int r = flat >> 3, c8 = flat & 7;
        int gr = rowBase + r;
        shortx8 v = {0,0,0,0,0,0,0,0};
        if (gr < NN) v = *(const shortx8*)&Apk[(size_t)gr*KPACK + k0 + c8*8];
        *(shortx8*)&sA[r*SAK + c8*8] = v;
      }
    } else {
      int kb = k0 + shalf*32;
      short tmp[32];
      const float* p;
      if (MODE == 2) p = (kb < HD) ? (A0 + (size_t)sgr*HD + kb) : (A1 + (size_t)sgr*HD + (kb - HD));
      else           p = A0 + (size_t)sgr*HD + kb;
      #pragma unroll
      for (int q4=0;q4<8;++q4){
        float4 f = (sgr < NN) ? *(const float4*)(p + q4*4) : make_float4(0.f,0.f,0.f,0.f);
        tmp[q4*4+0] = f2bf(f.x); tmp[q4*4+1] = f2bf(f.y);
        tmp[q4*4+2] = f2bf(f.z); tmp[q4*4+3] = f2bf(f.w);
      }
      #pragma unroll
      for (int q8=0;q8<4;++q8)
        *(shortx8*)&sA[srow*SAK + shalf*32 + q8*8] = *(shortx8*)&tmp[q8*8];
    }
    // ---- stage B ----
    if (NT == 8){
      int col = tid >> 1, kb = k0 + (tid&1)*32;
      #pragma unroll
      for (int q8=0;q8<4;++q8)
        *(shortx8*)&sB[col*SAK + (tid&1)*32 + q8*8] = *(const shortx8*)&Wt[(size_t)col*Kp + kb + q8*8];
    } else {
      if (tid < NT*32){
        int col = tid >> 1, kb = k0 + (tid&1)*32;
        #pragma unroll
        for (int q8=0;q8<4;++q8)
          *(shortx8*)&sB[col*SAK + (tid&1)*32 + q8*8] = *(const shortx8*)&Wt[(size_t)col*Kp + kb + q8*8];
      }
    }
    __syncthreads();
    // ---- MFMA ----
    #pragma unroll
    for (int ks=0; ks<2; ++ks){
      int kb = ks*32 + quad*8;
      shortx8 af0 = *(const shortx8*)&sA[(wave*32 +      l16)*SAK + kb];
      shortx8 af1 = *(const shortx8*)&sA[(wave*32 + 16 + l16)*SAK + kb];
      #pragma unroll
      for (int ct=0; ct<NT; ++ct){
        shortx8 bf = *(const shortx8*)&sB[(ct*16 + l16)*SAK + kb];
        acc[0][ct] = __builtin_amdgcn_mfma_f32_16x16x32_bf16(af0, bf, acc[0][ct], 0,0,0);
        acc[1][ct] = __builtin_amdgcn_mfma_f32_16x16x32_bf16(af1, bf, acc[1][ct], 0,0,0);
      }
    }
    __syncthreads();
  }

  // ---- epilogue ----
  if (MODE == 1){
    float asv[NT], adv[NT];
    #pragma unroll
    for (int ct=0;ct<NT;++ct){ asv[ct] = as_[ct*16+l16]; adv[ct] = ad_[ct*16+l16]; }
    #pragma unroll
    for (int t=0;t<2;++t)
      #pragma unroll
      for (int i=0;i<4;++i){
        int gr = rowBase + wave*32 + t*16 + quad*4 + i;
        float s=0.f, d=0.f;
        #pragma unroll
        for (int ct=0;ct<NT;++ct){
          float v = acc[t][ct][i];
          s = fmaf(v, asv[ct], s); d = fmaf(v, adv[ct], d);
          if (gr < NN) out[(size_t)gr*HD + ct*16 + l16] = v;
        }
        #pragma unroll
        for (int off=1; off<16; off<<=1){ s += __shfl_xor(s,off); d += __shfl_xor(d,off); }
        if (l16 == 0 && gr < NN){ es[gr] = s; ed[gr] = d; }
      }
  } else if (MODE == 2){
    float biasv[NT];
    #pragma unroll
    for (int ct=0;ct<NT;++ct) biasv[ct] = bias[ct*16+l16];
    #pragma unroll
    for (int t=0;t<2;++t)
      #pragma unroll
      for (int i=0;i<4;++i){
        int gr = rowBase + wave*32 + t*16 + quad*4 + i;
        if (gr < NN){
          #pragma unroll
          for (int ct=0;ct<NT;++ct){
            int c = ct*16 + l16;
            float g = 1.f/(1.f + __expf(-(acc[t][ct][i] + biasv[ct])));
            float x1 = A0[(size_t)gr*HD + c];
            float x2 = A1[(size_t)gr*HD + c];
            out[(size_t)gr*HD + c] = g*x1 + (1.f-g)*x2;
          }
        }
      }
  } else { // MODE 0 / 3 / 4 : +bias, LN(NCOL), relu
    float biasv[NT], gv[NT], bv[NT];
    #pragma unroll
    for (int ct=0;ct<NT;++ct){
      biasv[ct] = bias[ct*16+l16]; gv[ct] = gw[ct*16+l16]; bv[ct] = gb[ct*16+l16];
    }
    #pragma unroll
    for (int t=0;t<2;++t)
      #pragma unroll
      for (int i=0;i<4;++i){
        int gr = rowBase + wave*32 + t*16 + quad*4 + i;
        float v[NT]; float s=0.f, q=0.f;
        #pragma unroll
        for (int ct=0;ct<NT;++ct){
          v[ct] = acc[t][ct][i] + biasv[ct];
          s += v[ct]; q = fmaf(v[ct], v[ct], q);
        }
        #pragma unroll
        for (int off=1; off<16; off<<=1){ s += __shfl_xor(s,off); q += __shfl_xor(q,off); }
        float mean = s * (1.f/NCOL);
        float inv  = rsqrtf(q*(1.f/NCOL) - mean*mean + 1e-5f);
        if (gr < NN){
          #pragma unroll
          for (int ct=0;ct<NT;++ct)
            out[(size_t)gr*NCOL + ct*16 + l16] = fmaxf((v[ct]-mean)*inv*gv[ct] + bv[ct], 0.f);
        }
      }
  }
}

// ---------------- GAT aggregation: lane-parallel scores + shfl-broadcast gather ----
__launch_bounds__(256)
__global__ void gat_aggregate_kernel(const float* __restrict__ xw, const float* __restrict__ es,
                                     const float* __restrict__ ed, const int* __restrict__ row_start,
                                     const int* __restrict__ csr_src, const float* __restrict__ bgat,
                                     float* __restrict__ out){
  int gid = blockIdx.x*256 + threadIdx.x;
  int n = gid >> 6, lane = gid & 63;
  if (n >= NN) return;
  int beg = row_start[n], end = row_start[n+1];
  float edn = ed[n];
  float sc_self = lrelu(es[n] + edn);

  // chunk 0: one edge per lane, indices+scores in registers
  int i0 = beg + lane;
  bool v0 = i0 < end;
  int sA = v0 ? csr_src[i0] : 0;
  float eA = v0 ? lrelu(es[sA] + edn) : -3.0e38f;
  float m = fmaxf(sc_self, eA);
  for (int i = beg + 64 + lane; i < end; i += 64)
    m = fmaxf(m, lrelu(es[csr_src[i]] + edn));
  #pragma unroll
  for (int off=1; off<64; off<<=1) m = fmaxf(m, __shfl_xor(m, off));

  float wA = v0 ? __expf(eA - m) : 0.f;
  float wsum_l = wA;
  float wself = __expf(sc_self - m);          // wave-uniform
  float a0 = wself * xw[(size_t)n*HD + lane];
  float a1 = wself * xw[(size_t)n*HD + 64 + lane];

  int deg0 = min(end - beg, 64);
  int j = 0;
  for (; j + 4 <= deg0; j += 4){
    int s0=__shfl(sA,j), s1=__shfl(sA,j+1), s2=__shfl(sA,j+2), s3=__shfl(sA,j+3);
    float w0=__shfl(wA,j), w1=__shfl(wA,j+1), w2=__shfl(wA,j+2), w3=__shfl(wA,j+3);
    const float* p0 = xw + (size_t)s0*HD;
    const float* p1 = xw + (size_t)s1*HD;
    const float* p2 = xw + (size_t)s2*HD;
    const float* p3 = xw + (size_t)s3*HD;
    float x00=p0[lane], x01=p0[64+lane];
    float x10=p1[lane], x11=p1[64+lane];
    float x20=p2[lane], x21=p2[64+lane];
    float x30=p3[lane], x31=p3[64+lane];
    a0=fmaf(w0,x00,a0); a1=fmaf(w0,x01,a1);
    a0=fmaf(w1,x10,a0); a1=fmaf(w1,x11,a1);
    a0=fmaf(w2,x20,a0); a1=fmaf(w2,x21,a1);
    a0=fmaf(w3,x30,a0); a1=fmaf(w3,x31,a1);
  }
  for (; j < deg0; ++j){
    int s=__shfl(sA,j); float w=__shfl(wA,j);
    a0=fmaf(w,xw[(size_t)s*HD+lane],a0);
    a1=fmaf(w,xw[(size_t)s*HD+64+lane],a1);
  }
  // rare: degree > 64, chunked
  for (int c = beg + 64; c < end; c += 64){
    int i = c + lane;
    bool vb = i < end;
    int sB = vb ? csr_src[i] : 0;
    float wB = vb ? __expf(lrelu(es[sB] + edn) - m) : 0.f;
    wsum_l += wB;
    int degc = min(end - c, 64);
    for (int jj=0; jj<degc; ++jj){
      int s=__shfl(sB,jj); float w=__shfl(wB,jj);
      a0=fmaf(w,xw[(size_t)s*HD+lane],a0);
      a1=fmaf(w,xw[(size_t)s*HD+64+lane],a1);
    }
  }
  #pragma unroll
  for (int off=1; off<64; off<<=1) wsum_l += __shfl_xor(wsum_l, off);
  float dinv = 1.f/(wsum_l + wself + 1e-16f);
  out[(size_t)n*HD + lane]      = a0*dinv + bgat[lane];
  out[(size_t)n*HD + 64 + lane] = a1*dinv + bgat[64+lane];
}

// ---------------- GraphNorm ----------------
__launch_bounds__(256)
__global__ void gn_group_kernel(const float* __restrict__ x, const int* __restrict__ gstart,
                                const float* __restrict__ gnw, const float* __restrict__ gnms,
                                float* __restrict__ shiftv, float* __restrict__ scalev){
  int g = blockIdx.x;
  int n0 = gstart[g], n1 = gstart[g+1];
  int f = threadIdx.x & 127, half = threadIdx.x >> 7;
  float s = 0.f, q = 0.f;
  for (int n = n0 + half; n < n1; n += 2){
    float v = x[(size_t)n*HD + f];
    s += v; q = fmaf(v, v, q);
  }
  __shared__ float rs[256], rq[256];
  rs[threadIdx.x] = s; rq[threadIdx.x] = q;
  __syncthreads();
  if (threadIdx.x < 128){
    s = rs[threadIdx.x] + rs[threadIdx.x+128];
    q = rq[threadIdx.x] + rq[threadIdx.x+128];
    float c = fmaxf((float)(n1 - n0), 1.f);
    float mean = s / c;
    float ms = gnms[f];
    float var = q/c - mean*mean*ms*(2.f - ms);
    shiftv[g*HD+f] = ms*mean;
    scalev[g*HD+f] = gnw[f] / sqrtf(var + 1e-5f);
  }
}

template<bool RES>
__launch_bounds__(256)
__global__ void gn_norm_kernel(const float* __restrict__ x, const int* __restrict__ batch,
                               const float* __restrict__ shiftv, const float* __restrict__ scalev,
                               const float* __restrict__ gnb, const float* __restrict__ res,
                               float* __restrict__ out){
  int idx = blockIdx.x*256 + threadIdx.x;   // float4 index
  if (idx >= NN*32) return;
  int n = idx >> 5, c4 = idx & 31;
  int f = c4*4;
  int g = batch[n];
  float4 xv = *(const float4*)&x[(size_t)n*HD + f];
  float4 sh = *(const float4*)&shiftv[g*HD + f];
  float4 sc = *(const float4*)&scalev[g*HD + f];
  float4 bb = *(const float4*)&gnb[f];
  float4 v;
  v.x = fmaxf((xv.x - sh.x)*sc.x + bb.x, 0.f);
  v.y = fmaxf((xv.y - sh.y)*sc.y + bb.y, 0.f);
  v.z = fmaxf((xv.z - sh.z)*sc.z + bb.z, 0.f);
  v.w = fmaxf((xv.w - sh.w)*sc.w + bb.w, 0.f);
  if (RES){
    float4 r = *(const float4*)&res[(size_t)n*HD + f];
    v.x += r.x; v.y += r.y; v.z += r.z; v.w += r.w;
  }
  *(float4*)&out[(size_t)n*HD + f] = v;
}

// ---------------- fc2: [N,64]@[64,1] ----------------
__launch_bounds__(256)
__global__ void fc2_kernel(const float* __restrict__ x, const float* __restrict__ w,
                           const float* __restrict__ b, float* __restrict__ out){
  int gid = blockIdx.x*256 + threadIdx.x;
  int n = gid >> 6, lane = gid & 63;
  if (n >= NN) return;
  float v = x[(size_t)n*64 + lane] * w[lane];
  #pragma unroll
  for (int off=32; off; off>>=1) v += __shfl_down(v, off);
  if (lane == 0) out[n] = v + b[0];
}

// ---------------- launch ----------------
extern "C" void kernel_launch(void* const* d_in, const int* in_sizes, int n_in,
                              void* d_out, int out_size, void* d_ws, size_t ws_size,
                              hipStream_t stream){
  const float* rna    = (const float*)d_in[0];
  const float* ss     = (const float*)d_in[1];
  const int*   eidx   = (const int*)d_in[2];
  const int*   batch  = (const int*)d_in[3];
  const float* W_fuse = (const float*)d_in[4];
  const float* b_fuse = (const float*)d_in[5];
  const float* ln1_g  = (const float*)d_in[6];
  const float* ln1_b  = (const float*)d_in[7];
  const float* W_gat  = (const float*)d_in[8];
  const float* att_src= (const float*)d_in[9];
  const float* att_dst= (const float*)d_in[10];
  const float* b_gat  = (const float*)d_in[11];
  const float* gn_w   = (const float*)d_in[12];
  const float* gn_b   = (const float*)d_in[13];
  const float* gn_ms  = (const float*)d_in[14];
  const float* W_gate = (const float*)d_in[15];
  const float* b_gate = (const float*)d_in[16];
  const float* W_head = (const float*)d_in[17];
  const float* b_head = (const float*)d_in[18];
  const float* ln2_g  = (const float*)d_in[19];
  const float* ln2_b  = (const float*)d_in[20];
  const float* W_fc1  = (const float*)d_in[21];
  const float* b_fc1  = (const float*)d_in[22];
  const float* ln3_g  = (const float*)d_in[23];
  const float* ln3_b  = (const float*)d_in[24];
  const float* W_fc2  = (const float*)d_in[25];
  const float* b_fc2  = (const float*)d_in[26];
  float* outp = (float*)d_out;

  const int* srcl = eidx;
  const int* dstl = eidx + EE;

  char* base = (char*)d_ws;
  size_t off = 0;
  auto alloc = [&](size_t bytes)->void*{
    void* p = base + off; off = (off + bytes + 255) & ~(size_t)255; return p;
  };
  float* h    = (float*)alloc((size_t)NN*HD*4);
  float* h1   = (float*)alloc((size_t)NN*HD*4);
  float* h2   = (float*)alloc((size_t)NN*HD*4);
  float* xw   = (float*)alloc((size_t)NN*HD*4);
  float* y    = (float*)alloc((size_t)NN*HD*4);
  float* es   = (float*)alloc((size_t)NN*4);
  float* ed   = (float*)alloc((size_t)NN*4);
  float* shiftv = (float*)alloc(GG*HD*4);
  float* scalev = (float*)alloc(GG*HD*4);
  int* deg       = (int*)alloc((size_t)NN*4);
  int* row_start = (int*)alloc((size_t)(NN+1)*4);
  int* cursor    = (int*)alloc((size_t)NN*4);
  int* csr_src   = (int*)alloc((size_t)EE*4);
  int* blocksum  = (int*)alloc(256*4);
  int* gstart    = (int*)alloc((GG+1)*4);
  short* Abf     = (short*)alloc((size_t)NN*KPACK*2);
  short* Wt_fuse = (short*)alloc((size_t)128*KPACK*2);
  short* Wt_gat  = (short*)alloc((size_t)128*128*2);
  short* Wt_gate = (short*)alloc((size_t)128*256*2);
  short* Wt_head = (short*)alloc((size_t)128*128*2);
  short* Wt_fc1  = (short*)alloc((size_t)64*128*2);
  float* hg = xw;   // reuse
  float* t1 = y;    // reuse
  float* t2 = h;    // reuse

  const int NB  = (NN + 255)/256;
  const int GB  = (NN + 127)/128;
  const int EB  = (EE + 255)/256;
  const int WVB = (NN*64 + 255)/256;

  pack_kernel<<<(NN+1)/2, 256, 0, stream>>>(rna, ss, Abf);

  wprep_kernel<<<(128*KPACK+255)/256, 256, 0, stream>>>(W_fuse, Wt_fuse, KFUSE, 128, KPACK);
  wprep_kernel<<<(128*128+255)/256, 256, 0, stream>>>(W_gat,  Wt_gat,  128, 128, 128);
  wprep_kernel<<<(128*256+255)/256, 256, 0, stream>>>(W_gate, Wt_gate, 256, 128, 256);
  wprep_kernel<<<(128*128+255)/256, 256, 0, stream>>>(W_head, Wt_head, 128, 128, 128);
  wprep_kernel<<<( 64*128+255)/256, 256, 0, stream>>>(W_fc1,  Wt_fc1,  128,  64, 128);

  hipMemsetAsync(deg, 0, (size_t)NN*4, stream);
  hist_dst_kernel<<<EB, 256, 0, stream>>>(dstl, deg);
  scan1_kernel<<<NB, 256, 0, stream>>>(deg, row_start, blocksum);
  scan2_kernel<<<1, 256, 0, stream>>>(blocksum, NB);
  scan3_kernel<<<NB, 256, 0, stream>>>(row_start, blocksum, cursor);
  scatter_kernel<<<EB, 256, 0, stream>>>(srcl, dstl, cursor, csr_src);
  gstart_kernel<<<NB, 256, 0, stream>>>(batch, gstart);

  // fuse + LN1 + relu -> h
  mfma_gemm<0,8><<<GB, 256, 0, stream>>>(nullptr, nullptr, Abf, Wt_fuse, b_fuse, ln1_g, ln1_b,
                                         nullptr, nullptr, h, nullptr, nullptr, KPACK, KPACK);
  // ---- GAT layer 1 ----
  mfma_gemm<1,8><<<GB, 256, 0, stream>>>(h, nullptr, nullptr, Wt_gat, nullptr, nullptr, nullptr,
                                         att_src, att_dst, xw, es, ed, HD, HD);
  gat_aggregate_kernel<<<WVB, 256, 0, stream>>>(xw, es, ed, row_start, csr_src, b_gat, y);
  gn_group_kernel<<<GG, 256, 0, stream>>>(y, gstart, gn_w, gn_ms, shiftv, scalev);
  gn_norm_kernel<false><<<(NN*32+255)/256, 256, 0, stream>>>(y, batch, shiftv, scalev, gn_b, nullptr, h1);

  // ---- GAT layer 2 ----
  mfma_gemm<1,8><<<GB, 256, 0, stream>>>(h1, nullptr, nullptr, Wt_gat, nullptr, nullptr, nullptr,
                                         att_src, att_dst, xw, es, ed, HD, HD);
  gat_aggregate_kernel<<<WVB, 256, 0, stream>>>(xw, es, ed, row_start, csr_src, b_gat, y);
  gn_group_kernel<<<GG, 256, 0, stream>>>(y, gstart, gn_w, gn_ms, shiftv, scalev);
  gn_norm_kernel<true><<<(NN*32+255)/256, 256, 0, stream>>>(y, batch, shiftv, scalev, gn_b, h, h2);

  // gate combine -> hg
  mfma_gemm<2,8><<<GB, 256, 0, stream>>>(h1, h2, nullptr, Wt_gate, b_gate, nullptr, nullptr,
                                         nullptr, nullptr, hg, nullptr, nullptr, 256, 256);
  // head + LN2 + relu -> t1
  mfma_gemm<3,8><<<GB, 256, 0, stream>>>(hg, nullptr, nullptr, Wt_head, b_head, ln2_g, ln2_b,
                                         nullptr, nullptr, t1, nullptr, nullptr, HD, HD);
  // fc1 + LN3 + relu -> t2
  mfma_gemm<4,4><<<GB, 256, 0, stream>>>(t1, nullptr, nullptr, Wt_fc1, b_fc1, ln3_g, ln3_b,
                                         nullptr, nullptr, t2, nullptr, nullptr, HD, HD);
  // fc2 -> out
  fc2_kernel<<<WVB, 256, 0, stream>>>(t2, W_fc2, b_fc2, outp);
}

// Round 6
// 674.582 us; speedup vs baseline: 1.9559x; 1.0290x over previous
//
#include <hip/hip_runtime.h>
#include <hip/hip_bf16.h>
#include <math.h>

#define NN 50000
#define EE 800000
#define RNA_D 645
#define KFUSE 651
#define KPACK 704   // padded K for packed bf16 input (multiple of 64)
#define HD 128
#define GG 200
#define SAK 72   // LDS k-stride (bf16 elems): 64 + 8 pad

typedef __attribute__((ext_vector_type(8))) short shortx8;
typedef __attribute__((ext_vector_type(4))) float floatx4;

__device__ __forceinline__ float lrelu(float x){ return x >= 0.f ? x : 0.2f*x; }
__device__ __forceinline__ short f2bf(float x){
  union { __hip_bfloat16 h; short s; } u; u.h = __float2bfloat16(x); return u.s;
}

// ---------------- input pack: concat(rna,ss) -> bf16 [NN][KPACK], coalesced ----
__launch_bounds__(256)
__global__ void pack_kernel(const float* __restrict__ rna, const float* __restrict__ ss,
                            short* __restrict__ Abf){
  int row = blockIdx.x*2 + (threadIdx.x >> 7);
  int t = threadIdx.x & 127;
  if (row >= NN) return;
  const float* rrow = rna + (size_t)row*RNA_D;
  short* orow = Abf + (size_t)row*KPACK;
  #pragma unroll
  for (int j=0;j<6;++j){
    int c = t + j*128;
    if (c < KPACK){
      float v = 0.f;
      if (c < RNA_D) v = rrow[c];
      else if (c < KFUSE) v = ss[row*6 + (c - RNA_D)];
      orow[c] = f2bf(v);
    }
  }
}

// ---------------- graph prep ----------------
__global__ void hist_gstart_kernel(const int* __restrict__ dst, int* __restrict__ deg,
                                   const int* __restrict__ batch, int* __restrict__ gstart){
  int e = blockIdx.x*256 + threadIdx.x;
  if (e < EE) atomicAdd(&deg[dst[e]], 1);
  if (e < NN){
    int g = batch[e];
    if (e == 0){ for (int gg=0; gg<=g; ++gg) gstart[gg] = 0; }
    else { int gp = batch[e-1]; for (int gg=gp+1; gg<=g; ++gg) gstart[gg] = e; }
    if (e == NN-1){ for (int gg=g+1; gg<=GG; ++gg) gstart[gg] = NN; }
  }
}
__global__ void scan1_kernel(const int* __restrict__ deg, int* __restrict__ row_start,
                             int* __restrict__ blocksum){
  __shared__ int s[256];
  int i = blockIdx.x*256 + threadIdx.x;
  int v = (i < NN) ? deg[i] : 0;
  s[threadIdx.x] = v;
  __syncthreads();
  for (int off=1; off<256; off<<=1){
    int t = (threadIdx.x >= off) ? s[threadIdx.x-off] : 0;
    __syncthreads();
    s[threadIdx.x] += t;
    __syncthreads();
  }
  if (i < NN) row_start[i] = s[threadIdx.x] - v;
  if (threadIdx.x == 255) blocksum[blockIdx.x] = s[255];
}
__global__ void scan2_kernel(int* __restrict__ blocksum, int nb){
  __shared__ int s[256];
  int v = (threadIdx.x < nb) ? blocksum[threadIdx.x] : 0;
  s[threadIdx.x] = v;
  __syncthreads();
  for (int off=1; off<256; off<<=1){
    int t = (threadIdx.x >= off) ? s[threadIdx.x-off] : 0;
    __syncthreads();
    s[threadIdx.x] += t;
    __syncthreads();
  }
  blocksum[threadIdx.x] = s[threadIdx.x] - v;
}
__global__ void scan3_kernel(int* __restrict__ row_start, const int* __restrict__ blocksum,
                             int* __restrict__ cursor){
  int i = blockIdx.x*256 + threadIdx.x;
  if (i < NN){
    int v = row_start[i] + blocksum[blockIdx.x];
    row_start[i] = v;
    cursor[i] = v;
  }
  if (i == 0) row_start[NN] = EE;
}
__global__ void scatter_kernel(const int* __restrict__ srcl, const int* __restrict__ dstl,
                               int* __restrict__ cursor, int* __restrict__ csr_src){
  int e = blockIdx.x*256 + threadIdx.x;
  if (e >= EE) return;
  int d = dstl[e];
  int slot = atomicAdd(&cursor[d], 1);
  csr_src[slot] = srcl[e];
}

// ---------------- weight prep: all 5 weights, one kernel ----------------
__global__ void wprep_all_kernel(const float* __restrict__ Wf, const float* __restrict__ Wg,
                                 const float* __restrict__ Wgt, const float* __restrict__ Wh,
                                 const float* __restrict__ W1,
                                 short* __restrict__ Tf, short* __restrict__ Tg,
                                 short* __restrict__ Tgt, short* __restrict__ Th,
                                 short* __restrict__ T1){
  int idx = blockIdx.x*256 + threadIdx.x;
  const int S0=128*KPACK, S1=128*128, S2=128*256, S3=128*128, S4=64*128;
  if (idx < S0){ int n=idx/KPACK, k=idx-n*KPACK; Tf[idx]=f2bf(k<KFUSE ? Wf[k*128+n] : 0.f); return; }
  idx -= S0;
  if (idx < S1){ int n=idx>>7, k=idx&127; Tg[idx]=f2bf(Wg[k*128+n]); return; }
  idx -= S1;
  if (idx < S2){ int n=idx>>8, k=idx&255; Tgt[idx]=f2bf(Wgt[k*128+n]); return; }
  idx -= S2;
  if (idx < S3){ int n=idx>>7, k=idx&127; Th[idx]=f2bf(Wh[k*128+n]); return; }
  idx -= S3;
  if (idx < S4){ int n=idx>>7, k=idx&127; T1[idx]=f2bf(W1[k*64+n]); return; }
}

// ---------------- MFMA GEMM ----------------
// MODE 0: fuse   A=packed bf16 K=704  epi: +bias, LN(128), relu
// MODE 1: xw     A fp32 K=128         epi: store + es/ed (fused edge-score proj)
// MODE 2: gate   A=h1|h2 fp32 K=256   epi: sigmoid(+bias) combine h1/h2
// MODE 3: head   A fp32 K=128         epi: +bias, LN(128), relu
// MODE 4: fc1+fc2 A fp32 K=128 NT=4   epi: +bias, LN(64), relu, dot W_fc2 -> outp
template<int MODE, int NT>
__launch_bounds__(256)
__global__ void mfma_gemm(const float* __restrict__ A0, const float* __restrict__ A1,
                          const short* __restrict__ Apk,
                          const short* __restrict__ Wt, const float* __restrict__ bias,
                          const float* __restrict__ gw, const float* __restrict__ gb,
                          const float* __restrict__ as_, const float* __restrict__ ad_,
                          float* __restrict__ out, float* __restrict__ es, float* __restrict__ ed,
                          int K, int Kp){
  __shared__ short sA[128*SAK];
  __shared__ short sB[NT*16*SAK];
  const int tid  = threadIdx.x;
  const int wave = tid >> 6, lane = tid & 63;
  const int quad = lane >> 4, l16 = lane & 15;
  const int rowBase = blockIdx.x * 128;
  const int NCOL = NT*16;

  floatx4 acc[2][NT];
  #pragma unroll
  for (int t=0;t<2;++t)
    #pragma unroll
    for (int ct=0;ct<NT;++ct)
      #pragma unroll
      for (int j=0;j<4;++j) acc[t][ct][j] = 0.f;

  const int srow = tid >> 1, shalf = tid & 1;
  const int sgr = rowBase + srow;

  for (int k0 = 0; k0 < K; k0 += 64){
    // ---- stage A ----
    if (MODE == 0){
      #pragma unroll
      for (int j=0;j<4;++j){
        int flat = tid + j*256;
        int r = flat >> 3, c8 = flat & 7;
        int gr = rowBase + r;
        shortx8 v = {0,0,0,0,0,0,0,0};
        if (gr < NN) v = *(const shortx8*)&Apk[(size_t)gr*KPACK + k0 + c8*8];
        *(shortx8*)&sA[r*SAK + c8*8] = v;
      }
    } else {
      int kb = k0 + shalf*32;
      short tmp[32];
      const float* p;
      if (MODE == 2) p = (kb < HD) ? (A0 + (size_t)sgr*HD + kb) : (A1 + (size_t)sgr*HD + (kb - HD));
      else           p = A0 + (size_t)sgr*HD + kb;
      #pragma unroll
      for (int q4=0;q4<8;++q4){
        float4 f = (sgr < NN) ? *(const float4*)(p + q4*4) : make_float4(0.f,0.f,0.f,0.f);
        tmp[q4*4+0] = f2bf(f.x); tmp[q4*4+1] = f2bf(f.y);
        tmp[q4*4+2] = f2bf(f.z); tmp[q4*4+3] = f2bf(f.w);
      }
      #pragma unroll
      for (int q8=0;q8<4;++q8)
        *(shortx8*)&sA[srow*SAK + shalf*32 + q8*8] = *(shortx8*)&tmp[q8*8];
    }
    // ---- stage B ----
    if (NT == 8){
      int col = tid >> 1, kb = k0 + (tid&1)*32;
      #pragma unroll
      for (int q8=0;q8<4;++q8)
        *(shortx8*)&sB[col*SAK + (tid&1)*32 + q8*8] = *(const shortx8*)&Wt[(size_t)col*Kp + kb + q8*8];
    } else {
      if (tid < NT*32){
        int col = tid >> 1, kb = k0 + (tid&1)*32;
        #pragma unroll
        for (int q8=0;q8<4;++q8)
          *(shortx8*)&sB[col*SAK + (tid&1)*32 + q8*8] = *(const shortx8*)&Wt[(size_t)col*Kp + kb + q8*8];
      }
    }
    __syncthreads();
    // ---- MFMA ----
    #pragma unroll
    for (int ks=0; ks<2; ++ks){
      int kb = ks*32 + quad*8;
      shortx8 af0 = *(const shortx8*)&sA[(wave*32 +      l16)*SAK + kb];
      shortx8 af1 = *(const shortx8*)&sA[(wave*32 + 16 + l16)*SAK + kb];
      #pragma unroll
      for (int ct=0; ct<NT; ++ct){
        shortx8 bf = *(const shortx8*)&sB[(ct*16 + l16)*SAK + kb];
        acc[0][ct] = __builtin_amdgcn_mfma_f32_16x16x32_bf16(af0, bf, acc[0][ct], 0,0,0);
        acc[1][ct] = __builtin_amdgcn_mfma_f32_16x16x32_bf16(af1, bf, acc[1][ct], 0,0,0);
      }
    }
    __syncthreads();
  }

  // ---- epilogue ----
  if (MODE == 1){
    float asv[NT], adv[NT];
    #pragma unroll
    for (int ct=0;ct<NT;++ct){ asv[ct] = as_[ct*16+l16]; adv[ct] = ad_[ct*16+l16]; }
    #pragma unroll
    for (int t=0;t<2;++t)
      #pragma unroll
      for (int i=0;i<4;++i){
        int gr = rowBase + wave*32 + t*16 + quad*4 + i;
        float s=0.f, d=0.f;
        #pragma unroll
        for (int ct=0;ct<NT;++ct){
          float v = acc[t][ct][i];
          s = fmaf(v, asv[ct], s); d = fmaf(v, adv[ct], d);
          if (gr < NN) out[(size_t)gr*HD + ct*16 + l16] = v;
        }
        #pragma unroll
        for (int off=1; off<16; off<<=1){ s += __shfl_xor(s,off); d += __shfl_xor(d,off); }
        if (l16 == 0 && gr < NN){ es[gr] = s; ed[gr] = d; }
      }
  } else if (MODE == 2){
    float biasv[NT];
    #pragma unroll
    for (int ct=0;ct<NT;++ct) biasv[ct] = bias[ct*16+l16];
    #pragma unroll
    for (int t=0;t<2;++t)
      #pragma unroll
      for (int i=0;i<4;++i){
        int gr = rowBase + wave*32 + t*16 + quad*4 + i;
        if (gr < NN){
          #pragma unroll
          for (int ct=0;ct<NT;++ct){
            int c = ct*16 + l16;
            float g = 1.f/(1.f + __expf(-(acc[t][ct][i] + biasv[ct])));
            float x1 = A0[(size_t)gr*HD + c];
            float x2 = A1[(size_t)gr*HD + c];
            out[(size_t)gr*HD + c] = g*x1 + (1.f-g)*x2;
          }
        }
      }
  } else if (MODE == 4){
    // +bias, LN(64), relu, then dot with W_fc2 (= as_), +b_fc2 (= ad_[0]) -> es (=outp)
    float biasv[NT], gv[NT], bv[NT], w2v[NT];
    #pragma unroll
    for (int ct=0;ct<NT;++ct){
      biasv[ct] = bias[ct*16+l16]; gv[ct] = gw[ct*16+l16]; bv[ct] = gb[ct*16+l16];
      w2v[ct] = as_[ct*16+l16];
    }
    float b2 = ad_[0];
    #pragma unroll
    for (int t=0;t<2;++t)
      #pragma unroll
      for (int i=0;i<4;++i){
        int gr = rowBase + wave*32 + t*16 + quad*4 + i;
        float v[NT]; float s=0.f, q=0.f;
        #pragma unroll
        for (int ct=0;ct<NT;++ct){
          v[ct] = acc[t][ct][i] + biasv[ct];
          s += v[ct]; q = fmaf(v[ct], v[ct], q);
        }
        #pragma unroll
        for (int off=1; off<16; off<<=1){ s += __shfl_xor(s,off); q += __shfl_xor(q,off); }
        float mean = s * (1.f/NCOL);
        float inv  = rsqrtf(q*(1.f/NCOL) - mean*mean + 1e-5f);
        float p = 0.f;
        #pragma unroll
        for (int ct=0;ct<NT;++ct){
          float o = fmaxf((v[ct]-mean)*inv*gv[ct] + bv[ct], 0.f);
          p = fmaf(o, w2v[ct], p);
        }
        #pragma unroll
        for (int off=1; off<16; off<<=1) p += __shfl_xor(p, off);
        if (l16 == 0 && gr < NN) es[gr] = p + b2;
      }
  } else { // MODE 0 / 3 : +bias, LN(128), relu
    float biasv[NT], gv[NT], bv[NT];
    #pragma unroll
    for (int ct=0;ct<NT;++ct){
      biasv[ct] = bias[ct*16+l16]; gv[ct] = gw[ct*16+l16]; bv[ct] = gb[ct*16+l16];
    }
    #pragma unroll
    for (int t=0;t<2;++t)
      #pragma unroll
      for (int i=0;i<4;++i){
        int gr = rowBase + wave*32 + t*16 + quad*4 + i;
        float v[NT]; float s=0.f, q=0.f;
        #pragma unroll
        for (int ct=0;ct<NT;++ct){
          v[ct] = acc[t][ct][i] + biasv[ct];
          s += v[ct]; q = fmaf(v[ct], v[ct], q);
        }
        #pragma unroll
        for (int off=1; off<16; off<<=1){ s += __shfl_xor(s,off); q += __shfl_xor(q,off); }
        float mean = s * (1.f/NCOL);
        float inv  = rsqrtf(q*(1.f/NCOL) - mean*mean + 1e-5f);
        if (gr < NN){
          #pragma unroll
          for (int ct=0;ct<NT;++ct)
            out[(size_t)gr*NCOL + ct*16 + l16] = fmaxf((v[ct]-mean)*inv*gv[ct] + bv[ct], 0.f);
        }
      }
  }
}

// ---------------- GAT aggregation: float2 remap, lane-parallel scores, shfl gather ----
__launch_bounds__(256)
__global__ void gat_aggregate_kernel(const float* __restrict__ xw, const float* __restrict__ es,
                                     const float* __restrict__ ed, const int* __restrict__ row_start,
                                     const int* __restrict__ csr_src, const float* __restrict__ bgat,
                                     float* __restrict__ out){
  int gid = blockIdx.x*256 + threadIdx.x;
  int n = gid >> 6, lane = gid & 63;
  if (n >= NN) return;
  int beg = row_start[n], end = row_start[n+1];
  float edn = ed[n];
  float sc_self = lrelu(es[n] + edn);

  int i0 = beg + lane;
  bool v0 = i0 < end;
  int sA = v0 ? csr_src[i0] : 0;
  float eA = v0 ? lrelu(es[sA] + edn) : -3.0e38f;
  float m = fmaxf(sc_self, eA);
  for (int i = beg + 64 + lane; i < end; i += 64)
    m = fmaxf(m, lrelu(es[csr_src[i]] + edn));
  #pragma unroll
  for (int off=1; off<64; off<<=1) m = fmaxf(m, __shfl_xor(m, off));

  float wA = v0 ? __expf(eA - m) : 0.f;
  float wsum_l = wA;
  float wself = __expf(sc_self - m);
  float2 self2 = *(const float2*)&xw[(size_t)n*HD + 2*lane];
  float a0 = wself*self2.x, a1 = wself*self2.y;

  int deg0 = min(end - beg, 64);
  int j = 0;
  for (; j + 8 <= deg0; j += 8){
    int ss[8]; float ww[8]; float2 xv[8];
    #pragma unroll
    for (int u=0;u<8;++u){ ss[u]=__shfl(sA,j+u); ww[u]=__shfl(wA,j+u); }
    #pragma unroll
    for (int u=0;u<8;++u) xv[u] = *(const float2*)&xw[(size_t)ss[u]*HD + 2*lane];
    #pragma unroll
    for (int u=0;u<8;++u){ a0=fmaf(ww[u],xv[u].x,a0); a1=fmaf(ww[u],xv[u].y,a1); }
  }
  for (; j < deg0; ++j){
    int s=__shfl(sA,j); float w=__shfl(wA,j);
    float2 xv = *(const float2*)&xw[(size_t)s*HD + 2*lane];
    a0=fmaf(w,xv.x,a0); a1=fmaf(w,xv.y,a1);
  }
  // rare: degree > 64, chunked
  for (int c = beg + 64; c < end; c += 64){
    int i = c + lane;
    bool vb = i < end;
    int sB = vb ? csr_src[i] : 0;
    float wB = vb ? __expf(lrelu(es[sB] + edn) - m) : 0.f;
    wsum_l += wB;
    int degc = min(end - c, 64);
    for (int jj=0; jj<degc; ++jj){
      int s=__shfl(sB,jj); float w=__shfl(wB,jj);
      float2 xv = *(const float2*)&xw[(size_t)s*HD + 2*lane];
      a0=fmaf(w,xv.x,a0); a1=fmaf(w,xv.y,a1);
    }
  }
  #pragma unroll
  for (int off=1; off<64; off<<=1) wsum_l += __shfl_xor(wsum_l, off);
  float dinv = 1.f/(wsum_l + wself + 1e-16f);
  float2 b2 = *(const float2*)&bgat[2*lane];
  float2 o; o.x = a0*dinv + b2.x; o.y = a1*dinv + b2.y;
  *(float2*)&out[(size_t)n*HD + 2*lane] = o;
}

// ---------------- GraphNorm ----------------
__launch_bounds__(256)
__global__ void gn_group_kernel(const float* __restrict__ x, const int* __restrict__ gstart,
                                const float* __restrict__ gnw, const float* __restrict__ gnms,
                                float* __restrict__ shiftv, float* __restrict__ scalev){
  int g = blockIdx.x;
  int n0 = gstart[g], n1 = gstart[g+1];
  int f = threadIdx.x & 127, half = threadIdx.x >> 7;
  float s = 0.f, q = 0.f;
  for (int n = n0 + half; n < n1; n += 2){
    float v = x[(size_t)n*HD + f];
    s += v; q = fmaf(v, v, q);
  }
  __shared__ float rs[256], rq[256];
  rs[threadIdx.x] = s; rq[threadIdx.x] = q;
  __syncthreads();
  if (threadIdx.x < 128){
    s = rs[threadIdx.x] + rs[threadIdx.x+128];
    q = rq[threadIdx.x] + rq[threadIdx.x+128];
    float c = fmaxf((float)(n1 - n0), 1.f);
    float mean = s / c;
    float ms = gnms[f];
    float var = q/c - mean*mean*ms*(2.f - ms);
    shiftv[g*HD+f] = ms*mean;
    scalev[g*HD+f] = gnw[f] / sqrtf(var + 1e-5f);
  }
}

template<bool RES>
__launch_bounds__(256)
__global__ void gn_norm_kernel(const float* __restrict__ x, const int* __restrict__ batch,
                               const float* __restrict__ shiftv, const float* __restrict__ scalev,
                               const float* __restrict__ gnb, const float* __restrict__ res,
                               float* __restrict__ out){
  int idx = blockIdx.x*256 + threadIdx.x;   // float4 index
  if (idx >= NN*32) return;
  int n = idx >> 5, c4 = idx & 31;
  int f = c4*4;
  int g = batch[n];
  float4 xv = *(const float4*)&x[(size_t)n*HD + f];
  float4 sh = *(const float4*)&shiftv[g*HD + f];
  float4 sc = *(const float4*)&scalev[g*HD + f];
  float4 bb = *(const float4*)&gnb[f];
  float4 v;
  v.x = fmaxf((xv.x - sh.x)*sc.x + bb.x, 0.f);
  v.y = fmaxf((xv.y - sh.y)*sc.y + bb.y, 0.f);
  v.z = fmaxf((xv.z - sh.z)*sc.z + bb.z, 0.f);
  v.w = fmaxf((xv.w - sh.w)*sc.w + bb.w, 0.f);
  if (RES){
    float4 r = *(const float4*)&res[(size_t)n*HD + f];
    v.x += r.x; v.y += r.y; v.z += r.z; v.w += r.w;
  }
  *(float4*)&out[(size_t)n*HD + f] = v;
}

// ---------------- launch ----------------
extern "C" void kernel_launch(void* const* d_in, const int* in_sizes, int n_in,
                              void* d_out, int out_size, void* d_ws, size_t ws_size,
                              hipStream_t stream){
  const float* rna    = (const float*)d_in[0];
  const float* ss     = (const float*)d_in[1];
  const int*   eidx   = (const int*)d_in[2];
  const int*   batch  = (const int*)d_in[3];
  const float* W_fuse = (const float*)d_in[4];
  const float* b_fuse = (const float*)d_in[5];
  const float* ln1_g  = (const float*)d_in[6];
  const float* ln1_b  = (const float*)d_in[7];
  const float* W_gat  = (const float*)d_in[8];
  const float* att_src= (const float*)d_in[9];
  const float* att_dst= (const float*)d_in[10];
  const float* b_gat  = (const float*)d_in[11];
  const float* gn_w   = (const float*)d_in[12];
  const float* gn_b   = (const float*)d_in[13];
  const float* gn_ms  = (const float*)d_in[14];
  const float* W_gate = (const float*)d_in[15];
  const float* b_gate = (const float*)d_in[16];
  const float* W_head = (const float*)d_in[17];
  const float* b_head = (const float*)d_in[18];
  const float* ln2_g  = (const float*)d_in[19];
  const float* ln2_b  = (const float*)d_in[20];
  const float* W_fc1  = (const float*)d_in[21];
  const float* b_fc1  = (const float*)d_in[22];
  const float* ln3_g  = (const float*)d_in[23];
  const float* ln3_b  = (const float*)d_in[24];
  const float* W_fc2  = (const float*)d_in[25];
  const float* b_fc2  = (const float*)d_in[26];
  float* outp = (float*)d_out;

  const int* srcl = eidx;
  const int* dstl = eidx + EE;

  char* base = (char*)d_ws;
  size_t off = 0;
  auto alloc = [&](size_t bytes)->void*{
    void* p = base + off; off = (off + bytes + 255) & ~(size_t)255; return p;
  };
  float* h    = (float*)alloc((size_t)NN*HD*4);
  float* h1   = (float*)alloc((size_t)NN*HD*4);
  float* h2   = (float*)alloc((size_t)NN*HD*4);
  float* xw   = (float*)alloc((size_t)NN*HD*4);
  float* y    = (float*)alloc((size_t)NN*HD*4);
  float* es   = (float*)alloc((size_t)NN*4);
  float* ed   = (float*)alloc((size_t)NN*4);
  float* shiftv = (float*)alloc(GG*HD*4);
  float* scalev = (float*)alloc(GG*HD*4);
  int* deg       = (int*)alloc((size_t)NN*4);
  int* row_start = (int*)alloc((size_t)(NN+1)*4);
  int* cursor    = (int*)alloc((size_t)NN*4);
  int* csr_src   = (int*)alloc((size_t)EE*4);
  int* blocksum  = (int*)alloc(256*4);
  int* gstart    = (int*)alloc((GG+1)*4);
  short* Abf     = (short*)alloc((size_t)NN*KPACK*2);
  short* Wt_fuse = (short*)alloc((size_t)128*KPACK*2);
  short* Wt_gat  = (short*)alloc((size_t)128*128*2);
  short* Wt_gate = (short*)alloc((size_t)128*256*2);
  short* Wt_head = (short*)alloc((size_t)128*128*2);
  short* Wt_fc1  = (short*)alloc((size_t)64*128*2);
  float* hg = xw;   // reuse
  float* t1 = y;    // reuse

  const int NB  = (NN + 255)/256;
  const int GB  = (NN + 127)/128;
  const int EB  = (EE + 255)/256;
  const int WVB = (NN*64 + 255)/256;
  const int WPREP_TOT = 128*KPACK + 128*128 + 128*256 + 128*128 + 64*128;

  pack_kernel<<<(NN+1)/2, 256, 0, stream>>>(rna, ss, Abf);

  wprep_all_kernel<<<(WPREP_TOT+255)/256, 256, 0, stream>>>(
      W_fuse, W_gat, W_gate, W_head, W_fc1,
      Wt_fuse, Wt_gat, Wt_gate, Wt_head, Wt_fc1);

  hipMemsetAsync(deg, 0, (size_t)NN*4, stream);
  hist_gstart_kernel<<<EB, 256, 0, stream>>>(dstl, deg, batch, gstart);
  scan1_kernel<<<NB, 256, 0, stream>>>(deg, row_start, blocksum);
  scan2_kernel<<<1, 256, 0, stream>>>(blocksum, NB);
  scan3_kernel<<<NB, 256, 0, stream>>>(row_start, blocksum, cursor);
  scatter_kernel<<<EB, 256, 0, stream>>>(srcl, dstl, cursor, csr_src);

  // fuse + LN1 + relu -> h
  mfma_gemm<0,8><<<GB, 256, 0, stream>>>(nullptr, nullptr, Abf, Wt_fuse, b_fuse, ln1_g, ln1_b,
                                         nullptr, nullptr, h, nullptr, nullptr, KPACK, KPACK);
  // ---- GAT layer 1 ----
  mfma_gemm<1,8><<<GB, 256, 0, stream>>>(h, nullptr, nullptr, Wt_gat, nullptr, nullptr, nullptr,
                                         att_src, att_dst, xw, es, ed, HD, HD);
  gat_aggregate_kernel<<<WVB, 256, 0, stream>>>(xw, es, ed, row_start, csr_src, b_gat, y);
  gn_group_kernel<<<GG, 256, 0, stream>>>(y, gstart, gn_w, gn_ms, shiftv, scalev);
  gn_norm_kernel<false><<<(NN*32+255)/256, 256, 0, stream>>>(y, batch, shiftv, scalev, gn_b, nullptr, h1);

  // ---- GAT layer 2 ----
  mfma_gemm<1,8><<<GB, 256, 0, stream>>>(h1, nullptr, nullptr, Wt_gat, nullptr, nullptr, nullptr,
                                         att_src, att_dst, xw, es, ed, HD, HD);
  gat_aggregate_kernel<<<WVB, 256, 0, stream>>>(xw, es, ed, row_start, csr_src, b_gat, y);
  gn_group_kernel<<<GG, 256, 0, stream>>>(y, gstart, gn_w, gn_ms, shiftv, scalev);
  gn_norm_kernel<true><<<(NN*32+255)/256, 256, 0, stream>>>(y, batch, shiftv, scalev, gn_b, h, h2);

  // gate combine -> hg
  mfma_gemm<2,8><<<GB, 256, 0, stream>>>(h1, h2, nullptr, Wt_gate, b_gate, nullptr, nullptr,
                                         nullptr, nullptr, hg, nullptr, nullptr, 256, 256);
  // head + LN2 + relu -> t1
  mfma_gemm<3,8><<<GB, 256, 0, stream>>>(hg, nullptr, nullptr, Wt_head, b_head, ln2_g, ln2_b,
                                         nullptr, nullptr, t1, nullptr, nullptr, HD, HD);
  // fc1 + LN3 + relu + fc2 -> out
  mfma_gemm<4,4><<<GB, 256, 0, stream>>>(t1, nullptr, nullptr, Wt_fc1, b_fc1, ln3_g, ln3_b,
                                         W_fc2, b_fc2, nullptr, outp, nullptr, HD, HD);
}

// Round 7
// 623.927 us; speedup vs baseline: 2.1147x; 1.0812x over previous
//
#include <hip/hip_runtime.h>
#include <hip/hip_bf16.h>
#include <math.h>

#define NN 50000
#define EE 800000
#define RNA_D 645
#define KFUSE 651
#define KPACK 704
#define HD 128
#define GG 200
#define SAK 72    // LDS k-stride (bf16): 64+8 pad
#define HGS 136   // persistent LDS row stride (bf16) for tail buffer

typedef __attribute__((ext_vector_type(8))) short shortx8;
typedef __attribute__((ext_vector_type(4))) float floatx4;

__device__ __forceinline__ float lrelu(float x){ return x >= 0.f ? x : 0.2f*x; }
__device__ __forceinline__ short f2bf(float x){
  union { __hip_bfloat16 h; short s; } u; u.h = __float2bfloat16(x); return u.s;
}
__device__ __forceinline__ float bf2f(short s){
  union { float f; unsigned u; } c; c.u = ((unsigned)(unsigned short)s) << 16; return c.f;
}
__device__ __forceinline__ float2 upk(unsigned u){
  union { float f; unsigned v; } a, b;
  a.v = u << 16; b.v = u & 0xffff0000u;
  return make_float2(a.f, b.f);
}

// ---------------- input pack ----------------
__launch_bounds__(256)
__global__ void pack_kernel(const float* __restrict__ rna, const float* __restrict__ ss,
                            short* __restrict__ Abf){
  int row = blockIdx.x*2 + (threadIdx.x >> 7);
  int t = threadIdx.x & 127;
  if (row >= NN) return;
  const float* rrow = rna + (size_t)row*RNA_D;
  short* orow = Abf + (size_t)row*KPACK;
  #pragma unroll
  for (int j=0;j<6;++j){
    int c = t + j*128;
    if (c < KPACK){
      float v = 0.f;
      if (c < RNA_D) v = rrow[c];
      else if (c < KFUSE) v = ss[row*6 + (c - RNA_D)];
      orow[c] = f2bf(v);
    }
  }
}

// ---------------- graph prep ----------------
__global__ void hist_gstart_kernel(const int* __restrict__ dst, int* __restrict__ deg,
                                   const int* __restrict__ batch, int* __restrict__ gstart){
  int e = blockIdx.x*256 + threadIdx.x;
  if (e < EE) atomicAdd(&deg[dst[e]], 1);
  if (e < NN){
    int g = batch[e];
    if (e == 0){ for (int gg=0; gg<=g; ++gg) gstart[gg] = 0; }
    else { int gp = batch[e-1]; for (int gg=gp+1; gg<=g; ++gg) gstart[gg] = e; }
    if (e == NN-1){ for (int gg=g+1; gg<=GG; ++gg) gstart[gg] = NN; }
  }
}
__global__ void scan1_kernel(const int* __restrict__ deg, int* __restrict__ row_start,
                             int* __restrict__ blocksum){
  __shared__ int s[256];
  int i = blockIdx.x*256 + threadIdx.x;
  int v = (i < NN) ? deg[i] : 0;
  s[threadIdx.x] = v;
  __syncthreads();
  for (int off=1; off<256; off<<=1){
    int t = (threadIdx.x >= off) ? s[threadIdx.x-off] : 0;
    __syncthreads();
    s[threadIdx.x] += t;
    __syncthreads();
  }
  if (i < NN) row_start[i] = s[threadIdx.x] - v;
  if (threadIdx.x == 255) blocksum[blockIdx.x] = s[255];
}
__global__ void scan2_kernel(int* __restrict__ blocksum, int nb){
  __shared__ int s[256];
  int v = (threadIdx.x < nb) ? blocksum[threadIdx.x] : 0;
  s[threadIdx.x] = v;
  __syncthreads();
  for (int off=1; off<256; off<<=1){
    int t = (threadIdx.x >= off) ? s[threadIdx.x-off] : 0;
    __syncthreads();
    s[threadIdx.x] += t;
    __syncthreads();
  }
  blocksum[threadIdx.x] = s[threadIdx.x] - v;
}
__global__ void scan3_kernel(int* __restrict__ row_start, const int* __restrict__ blocksum,
                             int* __restrict__ cursor){
  int i = blockIdx.x*256 + threadIdx.x;
  if (i < NN){
    int v = row_start[i] + blocksum[blockIdx.x];
    row_start[i] = v;
    cursor[i] = v;
  }
  if (i == 0) row_start[NN] = EE;
}
__global__ void scatter_kernel(const int* __restrict__ srcl, const int* __restrict__ dstl,
                               int* __restrict__ cursor, int* __restrict__ csr_src){
  int e = blockIdx.x*256 + threadIdx.x;
  if (e >= EE) return;
  int d = dstl[e];
  int slot = atomicAdd(&cursor[d], 1);
  csr_src[slot] = srcl[e];
}

// ---------------- weight prep ----------------
__global__ void wprep_all_kernel(const float* __restrict__ Wf, const float* __restrict__ Wg,
                                 const float* __restrict__ Wgt, const float* __restrict__ Wh,
                                 const float* __restrict__ W1,
                                 short* __restrict__ Tf, short* __restrict__ Tg,
                                 short* __restrict__ Tgt, short* __restrict__ Th,
                                 short* __restrict__ T1){
  int idx = blockIdx.x*256 + threadIdx.x;
  const int S0=128*KPACK, S1=128*128, S2=128*256, S3=128*128, S4=64*128;
  if (idx < S0){ int n=idx/KPACK, k=idx-n*KPACK; Tf[idx]=f2bf(k<KFUSE ? Wf[k*128+n] : 0.f); return; }
  idx -= S0;
  if (idx < S1){ int n=idx>>7, k=idx&127; Tg[idx]=f2bf(Wg[k*128+n]); return; }
  idx -= S1;
  if (idx < S2){ int n=idx>>8, k=idx&255; Tgt[idx]=f2bf(Wgt[k*128+n]); return; }
  idx -= S2;
  if (idx < S3){ int n=idx>>7, k=idx&127; Th[idx]=f2bf(Wh[k*128+n]); return; }
  idx -= S3;
  if (idx < S4){ int n=idx>>7, k=idx&127; T1[idx]=f2bf(W1[k*64+n]); return; }
}

// ---------------- MFMA GEMM (modes 0,1) ----------------
// MODE 0: fuse  A=packed bf16 K=704  epi: +bias, LN(128), relu -> out (fp32)
// MODE 1: xw    A fp32 K=128         epi: store bf16 xw + es/ed
//   GNA=true: A-staging applies graphnorm (shiftv/scalev/gb) + relu, side-writes h1 fp32
template<int MODE, int NT, bool GNA>
__launch_bounds__(256)
__global__ void mfma_gemm(const float* __restrict__ A0,
                          const short* __restrict__ Apk,
                          const short* __restrict__ Wt, const float* __restrict__ bias,
                          const float* __restrict__ gw, const float* __restrict__ gb,
                          const float* __restrict__ as_, const float* __restrict__ ad_,
                          const int* __restrict__ batch, const float* __restrict__ gnsh,
                          const float* __restrict__ gnsc, float* __restrict__ side,
                          float* __restrict__ out, short* __restrict__ outb,
                          float* __restrict__ es, float* __restrict__ ed,
                          int K, int Kp){
  __shared__ short sA[128*SAK];
  __shared__ short sB[NT*16*SAK];
  const int tid  = threadIdx.x;
  const int wave = tid >> 6, lane = tid & 63;
  const int quad = lane >> 4, l16 = lane & 15;
  const int rowBase = blockIdx.x * 128;
  const int NCOL = NT*16;

  floatx4 acc[2][NT];
  #pragma unroll
  for (int t=0;t<2;++t)
    #pragma unroll
    for (int ct=0;ct<NT;++ct)
      #pragma unroll
      for (int j=0;j<4;++j) acc[t][ct][j] = 0.f;

  const int srow = tid >> 1, shalf = tid & 1;
  const int sgr = rowBase + srow;

  for (int k0 = 0; k0 < K; k0 += 64){
    // ---- stage A ----
    if (MODE == 0){
      #pragma unroll
      for (int j=0;j<4;++j){
        int flat = tid + j*256;
        int r = flat >> 3, c8 = flat & 7;
        int gr = rowBase + r;
        shortx8 v = {0,0,0,0,0,0,0,0};
        if (gr < NN) v = *(const shortx8*)&Apk[(size_t)gr*KPACK + k0 + c8*8];
        *(shortx8*)&sA[r*SAK + c8*8] = v;
      }
    } else {
      int kb = k0 + shalf*32;
      short tmp[32];
      if (GNA){
        int g = (sgr < NN) ? batch[sgr] : 0;
        const float* py  = A0 + (size_t)sgr*HD + kb;
        const float* psh = gnsh + g*HD + kb;
        const float* psc = gnsc + g*HD + kb;
        const float* pbb = gb + kb;
        #pragma unroll
        for (int q4=0;q4<8;++q4){
          float4 yv = (sgr < NN) ? *(const float4*)(py + q4*4) : make_float4(0.f,0.f,0.f,0.f);
          float4 sh = *(const float4*)(psh + q4*4);
          float4 sc = *(const float4*)(psc + q4*4);
          float4 bb = *(const float4*)(pbb + q4*4);
          float4 v;
          v.x = fmaxf((yv.x - sh.x)*sc.x + bb.x, 0.f);
          v.y = fmaxf((yv.y - sh.y)*sc.y + bb.y, 0.f);
          v.z = fmaxf((yv.z - sh.z)*sc.z + bb.z, 0.f);
          v.w = fmaxf((yv.w - sh.w)*sc.w + bb.w, 0.f);
          if (sgr < NN) *(float4*)&side[(size_t)sgr*HD + kb + q4*4] = v;
          tmp[q4*4+0]=f2bf(v.x); tmp[q4*4+1]=f2bf(v.y);
          tmp[q4*4+2]=f2bf(v.z); tmp[q4*4+3]=f2bf(v.w);
        }
      } else {
        const float* p = A0 + (size_t)sgr*HD + kb;
        #pragma unroll
        for (int q4=0;q4<8;++q4){
          float4 f = (sgr < NN) ? *(const float4*)(p + q4*4) : make_float4(0.f,0.f,0.f,0.f);
          tmp[q4*4+0]=f2bf(f.x); tmp[q4*4+1]=f2bf(f.y);
          tmp[q4*4+2]=f2bf(f.z); tmp[q4*4+3]=f2bf(f.w);
        }
      }
      #pragma unroll
      for (int q8=0;q8<4;++q8)
        *(shortx8*)&sA[srow*SAK + shalf*32 + q8*8] = *(shortx8*)&tmp[q8*8];
    }
    // ---- stage B ----
    {
      int col = tid >> 1, kb = k0 + (tid&1)*32;
      #pragma unroll
      for (int q8=0;q8<4;++q8)
        *(shortx8*)&sB[col*SAK + (tid&1)*32 + q8*8] = *(const shortx8*)&Wt[(size_t)col*Kp + kb + q8*8];
    }
    __syncthreads();
    // ---- MFMA ----
    #pragma unroll
    for (int ks=0; ks<2; ++ks){
      int kb = ks*32 + quad*8;
      shortx8 af0 = *(const shortx8*)&sA[(wave*32 +      l16)*SAK + kb];
      shortx8 af1 = *(const shortx8*)&sA[(wave*32 + 16 + l16)*SAK + kb];
      #pragma unroll
      for (int ct=0; ct<NT; ++ct){
        shortx8 bf = *(const shortx8*)&sB[(ct*16 + l16)*SAK + kb];
        acc[0][ct] = __builtin_amdgcn_mfma_f32_16x16x32_bf16(af0, bf, acc[0][ct], 0,0,0);
        acc[1][ct] = __builtin_amdgcn_mfma_f32_16x16x32_bf16(af1, bf, acc[1][ct], 0,0,0);
      }
    }
    __syncthreads();
  }

  // ---- epilogue ----
  if (MODE == 1){
    float asv[NT], adv[NT];
    #pragma unroll
    for (int ct=0;ct<NT;++ct){ asv[ct] = as_[ct*16+l16]; adv[ct] = ad_[ct*16+l16]; }
    #pragma unroll
    for (int t=0;t<2;++t)
      #pragma unroll
      for (int i=0;i<4;++i){
        int gr = rowBase + wave*32 + t*16 + quad*4 + i;
        float s=0.f, d=0.f;
        #pragma unroll
        for (int ct=0;ct<NT;++ct){
          float v = acc[t][ct][i];
          s = fmaf(v, asv[ct], s); d = fmaf(v, adv[ct], d);
          if (gr < NN) outb[(size_t)gr*HD + ct*16 + l16] = f2bf(v);
        }
        #pragma unroll
        for (int off=1; off<16; off<<=1){ s += __shfl_xor(s,off); d += __shfl_xor(d,off); }
        if (l16 == 0 && gr < NN){ es[gr] = s; ed[gr] = d; }
      }
  } else { // MODE 0: +bias, LN(128), relu
    float biasv[NT], gv[NT], bv[NT];
    #pragma unroll
    for (int ct=0;ct<NT;++ct){
      biasv[ct] = bias[ct*16+l16]; gv[ct] = gw[ct*16+l16]; bv[ct] = gb[ct*16+l16];
    }
    #pragma unroll
    for (int t=0;t<2;++t)
      #pragma unroll
      for (int i=0;i<4;++i){
        int gr = rowBase + wave*32 + t*16 + quad*4 + i;
        float v[NT]; float s=0.f, q=0.f;
        #pragma unroll
        for (int ct=0;ct<NT;++ct){
          v[ct] = acc[t][ct][i] + biasv[ct];
          s += v[ct]; q = fmaf(v[ct], v[ct], q);
        }
        #pragma unroll
        for (int off=1; off<16; off<<=1){ s += __shfl_xor(s,off); q += __shfl_xor(q,off); }
        float mean = s * (1.f/NCOL);
        float inv  = rsqrtf(q*(1.f/NCOL) - mean*mean + 1e-5f);
        if (gr < NN){
          #pragma unroll
          for (int ct=0;ct<NT;++ct)
            out[(size_t)gr*NCOL + ct*16 + l16] = fmaxf((v[ct]-mean)*inv*gv[ct] + bv[ct], 0.f);
        }
      }
  }
}

// ---------------- GAT aggregation: bf16 gather ----------------
__launch_bounds__(256)
__global__ void gat_aggregate_kernel(const short* __restrict__ xwb, const float* __restrict__ es,
                                     const float* __restrict__ ed, const int* __restrict__ row_start,
                                     const int* __restrict__ csr_src, const float* __restrict__ bgat,
                                     float* __restrict__ out){
  int gid = blockIdx.x*256 + threadIdx.x;
  int n = gid >> 6, lane = gid & 63;
  if (n >= NN) return;
  int beg = row_start[n], end = row_start[n+1];
  float edn = ed[n];
  float sc_self = lrelu(es[n] + edn);

  int i0 = beg + lane;
  bool v0 = i0 < end;
  int sA = v0 ? csr_src[i0] : 0;
  float eA = v0 ? lrelu(es[sA] + edn) : -3.0e38f;
  float m = fmaxf(sc_self, eA);
  for (int i = beg + 64 + lane; i < end; i += 64)
    m = fmaxf(m, lrelu(es[csr_src[i]] + edn));
  #pragma unroll
  for (int off=1; off<64; off<<=1) m = fmaxf(m, __shfl_xor(m, off));

  float wA = v0 ? __expf(eA - m) : 0.f;
  float wsum_l = wA;
  float wself = __expf(sc_self - m);
  float2 self2 = upk(*(const unsigned*)&xwb[(size_t)n*HD + 2*lane]);
  float a0 = wself*self2.x, a1 = wself*self2.y;

  int deg0 = min(end - beg, 64);
  int j = 0;
  for (; j + 8 <= deg0; j += 8){
    int ss[8]; float ww[8]; unsigned xv[8];
    #pragma unroll
    for (int u=0;u<8;++u){ ss[u]=__shfl(sA,j+u); ww[u]=__shfl(wA,j+u); }
    #pragma unroll
    for (int u=0;u<8;++u) xv[u] = *(const unsigned*)&xwb[(size_t)ss[u]*HD + 2*lane];
    #pragma unroll
    for (int u=0;u<8;++u){ float2 f=upk(xv[u]); a0=fmaf(ww[u],f.x,a0); a1=fmaf(ww[u],f.y,a1); }
  }
  for (; j < deg0; ++j){
    int s=__shfl(sA,j); float w=__shfl(wA,j);
    float2 f = upk(*(const unsigned*)&xwb[(size_t)s*HD + 2*lane]);
    a0=fmaf(w,f.x,a0); a1=fmaf(w,f.y,a1);
  }
  for (int c = beg + 64; c < end; c += 64){
    int i = c + lane;
    bool vb = i < end;
    int sB = vb ? csr_src[i] : 0;
    float wB = vb ? __expf(lrelu(es[sB] + edn) - m) : 0.f;
    wsum_l += wB;
    int degc = min(end - c, 64);
    for (int jj=0; jj<degc; ++jj){
      int s=__shfl(sB,jj); float w=__shfl(wB,jj);
      float2 f = upk(*(const unsigned*)&xwb[(size_t)s*HD + 2*lane]);
      a0=fmaf(w,f.x,a0); a1=fmaf(w,f.y,a1);
    }
  }
  #pragma unroll
  for (int off=1; off<64; off<<=1) wsum_l += __shfl_xor(wsum_l, off);
  float dinv = 1.f/(wsum_l + wself + 1e-16f);
  float2 b2 = *(const float2*)&bgat[2*lane];
  float2 o; o.x = a0*dinv + b2.x; o.y = a1*dinv + b2.y;
  *(float2*)&out[(size_t)n*HD + 2*lane] = o;
}

// ---------------- GraphNorm group stats ----------------
__launch_bounds__(256)
__global__ void gn_group_kernel(const float* __restrict__ x, const int* __restrict__ gstart,
                                const float* __restrict__ gnw, const float* __restrict__ gnms,
                                float* __restrict__ shiftv, float* __restrict__ scalev){
  int g = blockIdx.x;
  int n0 = gstart[g], n1 = gstart[g+1];
  int f = threadIdx.x & 127, half = threadIdx.x >> 7;
  float s = 0.f, q = 0.f;
  for (int n = n0 + half; n < n1; n += 2){
    float v = x[(size_t)n*HD + f];
    s += v; q = fmaf(v, v, q);
  }
  __shared__ float rs[256], rq[256];
  rs[threadIdx.x] = s; rq[threadIdx.x] = q;
  __syncthreads();
  if (threadIdx.x < 128){
    s = rs[threadIdx.x] + rs[threadIdx.x+128];
    q = rq[threadIdx.x] + rq[threadIdx.x+128];
    float c = fmaxf((float)(n1 - n0), 1.f);
    float mean = s / c;
    float ms = gnms[f];
    float var = q/c - mean*mean*ms*(2.f - ms);
    shiftv[g*HD+f] = ms*mean;
    scalev[g*HD+f] = gnw[f] / sqrtf(var + 1e-5f);
  }
}

// ---------------- tail: gate + head(+LN2) + fc1(+LN3) + fc2 ----------------
__launch_bounds__(256)
__global__ void tail_kernel(const float* __restrict__ h1, const float* __restrict__ y2,
                            const float* __restrict__ hres, const int* __restrict__ batch,
                            const float* __restrict__ gnsh, const float* __restrict__ gnsc,
                            const float* __restrict__ gnb,
                            const short* __restrict__ Wt_gate, const float* __restrict__ b_gate,
                            const short* __restrict__ Wt_head, const float* __restrict__ b_head,
                            const float* __restrict__ ln2g, const float* __restrict__ ln2b,
                            const short* __restrict__ Wt_fc1, const float* __restrict__ b_fc1,
                            const float* __restrict__ ln3g, const float* __restrict__ ln3b,
                            const float* __restrict__ W_fc2, const float* __restrict__ b_fc2,
                            float* __restrict__ outp){
  __shared__ short hgL[128*HGS];   // persistent: h2 -> hg -> t1
  __shared__ short sA[128*SAK];
  __shared__ short sB[128*SAK];
  const int tid = threadIdx.x, wave = tid>>6, lane = tid&63;
  const int quad = lane>>4, l16 = lane&15;
  const int rowBase = blockIdx.x*128;
  const int srow = tid>>1, shalf = tid&1;
  const int sgr = rowBase + srow;

  // ===== stage 1: gate GEMM, K=256 (A = [h1 | h2=gn(y2)+hres]) =====
  floatx4 acc[2][8];
  #pragma unroll
  for (int t=0;t<2;++t)
    #pragma unroll
    for (int ct=0;ct<8;++ct)
      #pragma unroll
      for (int j=0;j<4;++j) acc[t][ct][j]=0.f;

  for (int c2=0; c2<4; ++c2){
    int kb = c2*64 + shalf*32;
    short tmp[32];
    if (kb < 128){
      const float* p = h1 + (size_t)sgr*HD + kb;
      #pragma unroll
      for (int q4=0;q4<8;++q4){
        float4 f = (sgr < NN) ? *(const float4*)(p + q4*4) : make_float4(0.f,0.f,0.f,0.f);
        tmp[q4*4+0]=f2bf(f.x); tmp[q4*4+1]=f2bf(f.y);
        tmp[q4*4+2]=f2bf(f.z); tmp[q4*4+3]=f2bf(f.w);
      }
    } else {
      int cb = kb - 128;
      int g = (sgr < NN) ? batch[sgr] : 0;
      const float* py  = y2   + (size_t)sgr*HD + cb;
      const float* ph  = hres + (size_t)sgr*HD + cb;
      const float* psh = gnsh + g*HD + cb;
      const float* psc = gnsc + g*HD + cb;
      const float* pbb = gnb + cb;
      #pragma unroll
      for (int q4=0;q4<8;++q4){
        float4 yv = (sgr < NN) ? *(const float4*)(py + q4*4) : make_float4(0.f,0.f,0.f,0.f);
        float4 hv = (sgr < NN) ? *(const float4*)(ph + q4*4) : make_float4(0.f,0.f,0.f,0.f);
        float4 sh = *(const float4*)(psh + q4*4);
        float4 sc = *(const float4*)(psc + q4*4);
        float4 bb = *(const float4*)(pbb + q4*4);
        float4 v;
        v.x = fmaxf((yv.x - sh.x)*sc.x + bb.x, 0.f) + hv.x;
        v.y = fmaxf((yv.y - sh.y)*sc.y + bb.y, 0.f) + hv.y;
        v.z = fmaxf((yv.z - sh.z)*sc.z + bb.z, 0.f) + hv.z;
        v.w = fmaxf((yv.w - sh.w)*sc.w + bb.w, 0.f) + hv.w;
        tmp[q4*4+0]=f2bf(v.x); tmp[q4*4+1]=f2bf(v.y);
        tmp[q4*4+2]=f2bf(v.z); tmp[q4*4+3]=f2bf(v.w);
      }
      // persist h2 (bf16) into hgL
      #pragma unroll
      for (int q8=0;q8<4;++q8)
        *(shortx8*)&hgL[srow*HGS + cb + q8*8] = *(shortx8*)&tmp[q8*8];
    }
    #pragma unroll
    for (int q8=0;q8<4;++q8)
      *(shortx8*)&sA[srow*SAK + shalf*32 + q8*8] = *(shortx8*)&tmp[q8*8];
    // stage B (Wt_gate: [128][256])
    {
      int col = tid >> 1, kb2 = c2*64 + (tid&1)*32;
      #pragma unroll
      for (int q8=0;q8<4;++q8)
        *(shortx8*)&sB[col*SAK + (tid&1)*32 + q8*8] = *(const shortx8*)&Wt_gate[(size_t)col*256 + kb2 + q8*8];
    }
    __syncthreads();
    #pragma unroll
    for (int ks=0; ks<2; ++ks){
      int kk = ks*32 + quad*8;
      shortx8 af0 = *(const shortx8*)&sA[(wave*32 +      l16)*SAK + kk];
      shortx8 af1 = *(const shortx8*)&sA[(wave*32 + 16 + l16)*SAK + kk];
      #pragma unroll
      for (int ct=0; ct<8; ++ct){
        shortx8 bf = *(const shortx8*)&sB[(ct*16 + l16)*SAK + kk];
        acc[0][ct] = __builtin_amdgcn_mfma_f32_16x16x32_bf16(af0, bf, acc[0][ct], 0,0,0);
        acc[1][ct] = __builtin_amdgcn_mfma_f32_16x16x32_bf16(af1, bf, acc[1][ct], 0,0,0);
      }
    }
    __syncthreads();
  }
  // gate epilogue: hg = g*h1 + (1-g)*h2  -> hgL (bf16, overwrite h2 slot per owned element)
  {
    float biasv[8];
    #pragma unroll
    for (int ct=0;ct<8;++ct) biasv[ct] = b_gate[ct*16+l16];
    #pragma unroll
    for (int t=0;t<2;++t)
      #pragma unroll
      for (int i=0;i<4;++i){
        int row = wave*32 + t*16 + quad*4 + i;
        int gr = rowBase + row;
        #pragma unroll
        for (int ct=0;ct<8;++ct){
          int c = ct*16 + l16;
          float g = 1.f/(1.f + __expf(-(acc[t][ct][i] + biasv[ct])));
          float x1 = (gr < NN) ? h1[(size_t)gr*HD + c] : 0.f;
          float x2 = bf2f(hgL[row*HGS + c]);
          hgL[row*HGS + c] = f2bf(g*x1 + (1.f-g)*x2);
        }
      }
  }
  __syncthreads();

  // ===== stage 2: head GEMM K=128, A=hgL, +bias LN(128) relu -> hgL =====
  floatx4 acc2[2][8];
  #pragma unroll
  for (int t=0;t<2;++t)
    #pragma unroll
    for (int ct=0;ct<8;++ct)
      #pragma unroll
      for (int j=0;j<4;++j) acc2[t][ct][j]=0.f;
  for (int c2=0;c2<2;++c2){
    {
      int col = tid >> 1, kb2 = c2*64 + (tid&1)*32;
      #pragma unroll
      for (int q8=0;q8<4;++q8)
        *(shortx8*)&sB[col*SAK + (tid&1)*32 + q8*8] = *(const shortx8*)&Wt_head[(size_t)col*128 + kb2 + q8*8];
    }
    __syncthreads();
    #pragma unroll
    for (int ks=0; ks<2; ++ks){
      int kg = c2*64 + ks*32 + quad*8;
      int kk = ks*32 + quad*8;
      shortx8 af0 = *(const shortx8*)&hgL[(wave*32 +      l16)*HGS + kg];
      shortx8 af1 = *(const shortx8*)&hgL[(wave*32 + 16 + l16)*HGS + kg];
      #pragma unroll
      for (int ct=0; ct<8; ++ct){
        shortx8 bf = *(const shortx8*)&sB[(ct*16 + l16)*SAK + kk];
        acc2[0][ct] = __builtin_amdgcn_mfma_f32_16x16x32_bf16(af0, bf, acc2[0][ct], 0,0,0);
        acc2[1][ct] = __builtin_amdgcn_mfma_f32_16x16x32_bf16(af1, bf, acc2[1][ct], 0,0,0);
      }
    }
    __syncthreads();
  }
  // head epilogue: LN(128) relu -> hgL (t1, bf16)
  {
    float biasv[8], gv[8], bv[8];
    #pragma unroll
    for (int ct=0;ct<8;++ct){
      biasv[ct] = b_head[ct*16+l16]; gv[ct] = ln2g[ct*16+l16]; bv[ct] = ln2b[ct*16+l16];
    }
    #pragma unroll
    for (int t=0;t<2;++t)
      #pragma unroll
      for (int i=0;i<4;++i){
        int row = wave*32 + t*16 + quad*4 + i;
        float v[8]; float s=0.f, q=0.f;
        #pragma unroll
        for (int ct=0;ct<8;++ct){
          v[ct] = acc2[t][ct][i] + biasv[ct];
          s += v[ct]; q = fmaf(v[ct], v[ct], q);
        }
        #pragma unroll
        for (int off=1; off<16; off<<=1){ s += __shfl_xor(s,off); q += __shfl_xor(q,off); }
        float mean = s * (1.f/128.f);
        float inv  = rsqrtf(q*(1.f/128.f) - mean*mean + 1e-5f);
        #pragma unroll
        for (int ct=0;ct<8;++ct)
          hgL[row*HGS + ct*16 + l16] = f2bf(fmaxf((v[ct]-mean)*inv*gv[ct] + bv[ct], 0.f));
      }
  }
  __syncthreads();

  // ===== stage 3: fc1 K=128 -> 64 cols, LN(64), relu, dot W_fc2 -> outp =====
  floatx4 acc3[2][4];
  #pragma unroll
  for (int t=0;t<2;++t)
    #pragma unroll
    for (int ct=0;ct<4;++ct)
      #pragma unroll
      for (int j=0;j<4;++j) acc3[t][ct][j]=0.f;
  for (int c2=0;c2<2;++c2){
    if (tid < 128){
      int col = tid >> 1, kb2 = c2*64 + (tid&1)*32;
      #pragma unroll
      for (int q8=0;q8<4;++q8)
        *(shortx8*)&sB[col*SAK + (tid&1)*32 + q8*8] = *(const shortx8*)&Wt_fc1[(size_t)col*128 + kb2 + q8*8];
    }
    __syncthreads();
    #pragma unroll
    for (int ks=0; ks<2; ++ks){
      int kg = c2*64 + ks*32 + quad*8;
      int kk = ks*32 + quad*8;
      shortx8 af0 = *(const shortx8*)&hgL[(wave*32 +      l16)*HGS + kg];
      shortx8 af1 = *(const shortx8*)&hgL[(wave*32 + 16 + l16)*HGS + kg];
      #pragma unroll
      for (int ct=0; ct<4; ++ct){
        shortx8 bf = *(const shortx8*)&sB[(ct*16 + l16)*SAK + kk];
        acc3[0][ct] = __builtin_amdgcn_mfma_f32_16x16x32_bf16(af0, bf, acc3[0][ct], 0,0,0);
        acc3[1][ct] = __builtin_amdgcn_mfma_f32_16x16x32_bf16(af1, bf, acc3[1][ct], 0,0,0);
      }
    }
    __syncthreads();
  }
  {
    float biasv[4], gv[4], bv[4], w2v[4];
    #pragma unroll
    for (int ct=0;ct<4;++ct){
      biasv[ct] = b_fc1[ct*16+l16]; gv[ct] = ln3g[ct*16+l16]; bv[ct] = ln3b[ct*16+l16];
      w2v[ct] = W_fc2[ct*16+l16];
    }
    float b2 = b_fc2[0];
    #pragma unroll
    for (int t=0;t<2;++t)
      #pragma unroll
      for (int i=0;i<4;++i){
        int gr = rowBase + wave*32 + t*16 + quad*4 + i;
        float v[4]; float s=0.f, q=0.f;
        #pragma unroll
        for (int ct=0;ct<4;++ct){
          v[ct] = acc3[t][ct][i] + biasv[ct];
          s += v[ct]; q = fmaf(v[ct], v[ct], q);
        }
        #pragma unroll
        for (int off=1; off<16; off<<=1){ s += __shfl_xor(s,off); q += __shfl_xor(q,off); }
        float mean = s * (1.f/64.f);
        float inv  = rsqrtf(q*(1.f/64.f) - mean*mean + 1e-5f);
        float p = 0.f;
        #pragma unroll
        for (int ct=0;ct<4;++ct){
          float o = fmaxf((v[ct]-mean)*inv*gv[ct] + bv[ct], 0.f);
          p = fmaf(o, w2v[ct], p);
        }
        #pragma unroll
        for (int off=1; off<16; off<<=1) p += __shfl_xor(p, off);
        if (l16 == 0 && gr < NN) outp[gr] = p + b2;
      }
  }
}

// ---------------- launch ----------------
extern "C" void kernel_launch(void* const* d_in, const int* in_sizes, int n_in,
                              void* d_out, int out_size, void* d_ws, size_t ws_size,
                              hipStream_t stream){
  const float* rna    = (const float*)d_in[0];
  const float* ss     = (const float*)d_in[1];
  const int*   eidx   = (const int*)d_in[2];
  const int*   batch  = (const int*)d_in[3];
  const float* W_fuse = (const float*)d_in[4];
  const float* b_fuse = (const float*)d_in[5];
  const float* ln1_g  = (const float*)d_in[6];
  const float* ln1_b  = (const float*)d_in[7];
  const float* W_gat  = (const float*)d_in[8];
  const float* att_src= (const float*)d_in[9];
  const float* att_dst= (const float*)d_in[10];
  const float* b_gat  = (const float*)d_in[11];
  const float* gn_w   = (const float*)d_in[12];
  const float* gn_b   = (const float*)d_in[13];
  const float* gn_ms  = (const float*)d_in[14];
  const float* W_gate = (const float*)d_in[15];
  const float* b_gate = (const float*)d_in[16];
  const float* W_head = (const float*)d_in[17];
  const float* b_head = (const float*)d_in[18];
  const float* ln2_g  = (const float*)d_in[19];
  const float* ln2_b  = (const float*)d_in[20];
  const float* W_fc1  = (const float*)d_in[21];
  const float* b_fc1  = (const float*)d_in[22];
  const float* ln3_g  = (const float*)d_in[23];
  const float* ln3_b  = (const float*)d_in[24];
  const float* W_fc2  = (const float*)d_in[25];
  const float* b_fc2  = (const float*)d_in[26];
  float* outp = (float*)d_out;

  const int* srcl = eidx;
  const int* dstl = eidx + EE;

  char* base = (char*)d_ws;
  size_t off = 0;
  auto alloc = [&](size_t bytes)->void*{
    void* p = base + off; off = (off + bytes + 255) & ~(size_t)255; return p;
  };
  float* h    = (float*)alloc((size_t)NN*HD*4);
  float* h1   = (float*)alloc((size_t)NN*HD*4);
  float* y    = (float*)alloc((size_t)NN*HD*4);
  short* xwb  = (short*)alloc((size_t)NN*HD*2);
  float* es   = (float*)alloc((size_t)NN*4);
  float* ed   = (float*)alloc((size_t)NN*4);
  float* shiftv = (float*)alloc(GG*HD*4);
  float* scalev = (float*)alloc(GG*HD*4);
  int* deg       = (int*)alloc((size_t)NN*4);
  int* row_start = (int*)alloc((size_t)(NN+1)*4);
  int* cursor    = (int*)alloc((size_t)NN*4);
  int* csr_src   = (int*)alloc((size_t)EE*4);
  int* blocksum  = (int*)alloc(256*4);
  int* gstart    = (int*)alloc((GG+1)*4);
  short* Abf     = (short*)alloc((size_t)NN*KPACK*2);
  short* Wt_fuse = (short*)alloc((size_t)128*KPACK*2);
  short* Wt_gat  = (short*)alloc((size_t)128*128*2);
  short* Wt_gate = (short*)alloc((size_t)128*256*2);
  short* Wt_head = (short*)alloc((size_t)128*128*2);
  short* Wt_fc1  = (short*)alloc((size_t)64*128*2);

  const int NB  = (NN + 255)/256;
  const int GB  = (NN + 127)/128;
  const int EB  = (EE + 255)/256;
  const int WVB = (NN*64 + 255)/256;
  const int WPREP_TOT = 128*KPACK + 128*128 + 128*256 + 128*128 + 64*128;

  pack_kernel<<<(NN+1)/2, 256, 0, stream>>>(rna, ss, Abf);
  wprep_all_kernel<<<(WPREP_TOT+255)/256, 256, 0, stream>>>(
      W_fuse, W_gat, W_gate, W_head, W_fc1,
      Wt_fuse, Wt_gat, Wt_gate, Wt_head, Wt_fc1);

  hipMemsetAsync(deg, 0, (size_t)NN*4, stream);
  hist_gstart_kernel<<<EB, 256, 0, stream>>>(dstl, deg, batch, gstart);
  scan1_kernel<<<NB, 256, 0, stream>>>(deg, row_start, blocksum);
  scan2_kernel<<<1, 256, 0, stream>>>(blocksum, NB);
  scan3_kernel<<<NB, 256, 0, stream>>>(row_start, blocksum, cursor);
  scatter_kernel<<<EB, 256, 0, stream>>>(srcl, dstl, cursor, csr_src);

  // fuse + LN1 + relu -> h
  mfma_gemm<0,8,false><<<GB, 256, 0, stream>>>(nullptr, Abf, Wt_fuse, b_fuse, ln1_g, ln1_b,
      nullptr, nullptr, nullptr, nullptr, nullptr, nullptr, h, nullptr, nullptr, nullptr, KPACK, KPACK);

  // ---- GAT layer 1 ----
  mfma_gemm<1,8,false><<<GB, 256, 0, stream>>>(h, nullptr, Wt_gat, nullptr, nullptr, nullptr,
      att_src, att_dst, nullptr, nullptr, nullptr, nullptr, nullptr, xwb, es, ed, HD, HD);
  gat_aggregate_kernel<<<WVB, 256, 0, stream>>>(xwb, es, ed, row_start, csr_src, b_gat, y);
  gn_group_kernel<<<GG, 256, 0, stream>>>(y, gstart, gn_w, gn_ms, shiftv, scalev);

  // ---- GAT layer 2 (graphnorm fused into staging, side-writes h1) ----
  mfma_gemm<1,8,true><<<GB, 256, 0, stream>>>(y, nullptr, Wt_gat, nullptr, nullptr, gn_b,
      att_src, att_dst, batch, shiftv, scalev, h1, nullptr, xwb, es, ed, HD, HD);
  gat_aggregate_kernel<<<WVB, 256, 0, stream>>>(xwb, es, ed, row_start, csr_src, b_gat, y);
  gn_group_kernel<<<GG, 256, 0, stream>>>(y, gstart, gn_w, gn_ms, shiftv, scalev);

  // ---- tail: gate + head + fc1 + fc2 -> out ----
  tail_kernel<<<GB, 256, 0, stream>>>(h1, y, h, batch, shiftv, scalev, gn_b,
      Wt_gate, b_gate, Wt_head, b_head, ln2_g, ln2_b,
      Wt_fc1, b_fc1, ln3_g, ln3_b, W_fc2, b_fc2, outp);
}